// Round 4
// baseline (1049.487 us; speedup 1.0000x reference)
//
#include <hip/hip_runtime.h>

typedef _Float16 f16;
typedef _Float16 f16x8 __attribute__((ext_vector_type(8)));
typedef _Float16 f16x4 __attribute__((ext_vector_type(4)));
typedef float f32x4 __attribute__((ext_vector_type(4)));

#define MFMA16(a, b, c) __builtin_amdgcn_mfma_f32_16x16x32_f16(a, b, c, 0, 0, 0)

__device__ __forceinline__ f16x8 cvt8(const float* p) {
  const float4* s = (const float4*)p;
  float4 u0 = s[0], u1 = s[1];
  f16x8 v;
  v[0] = (f16)u0.x; v[1] = (f16)u0.y; v[2] = (f16)u0.z; v[3] = (f16)u0.w;
  v[4] = (f16)u1.x; v[5] = (f16)u1.y; v[6] = (f16)u1.z; v[7] = (f16)u1.w;
  return v;
}

// ---- prep: W_qkv / W_out -> f16 fragment-linear layout in ws ----
// frag (kc, nt, lane l): idx16 = nt*16 + (l&15), k = kc*32 + (l>>4)*8 .. +8
__global__ void wmsa_prep(const float* __restrict__ Wqkv,
                          const float* __restrict__ Wout,
                          f16* __restrict__ ws) {
  int gid = blockIdx.x * 256 + threadIdx.x;
  if (gid < 13824) {
    int fb = gid >> 6, l = gid & 63;
    int kc = fb / 36, nt = fb - kc * 36;
    int n = nt * 16 + (l & 15), k = kc * 32 + (l >> 4) * 8;
    *(f16x8*)(ws + (size_t)gid * 8) = cvt8(Wqkv + (size_t)n * 192 + k);
  } else if (gid < 18432) {
    int g2 = gid - 13824;
    int fb = g2 >> 6, l = g2 & 63;
    int kc = fb / 12, nt = fb - kc * 12;
    int n = nt * 16 + (l & 15), k = kc * 32 + (l >> 4) * 8;
    *(f16x8*)(ws + 110592 + (size_t)g2 * 8) = cvt8(Wout + (size_t)n * 192 + k);
  }
}

template <bool USE_WS>
__device__ __forceinline__ f16x8 load_bq(const f16* wsq, const float* Wqkv,
                                         int kc, int nt, int l) {
  if constexpr (USE_WS) {
    return *(const f16x8*)(wsq + (size_t)(kc * 36 + nt) * 512 + l * 8);
  } else {
    int n = nt * 16 + (l & 15), k = kc * 32 + (l >> 4) * 8;
    return cvt8(Wqkv + (size_t)n * 192 + k);
  }
}

template <bool USE_WS>
__device__ __forceinline__ f16x8 load_bo(const f16* wsq, const float* Wout,
                                         int kc, int nt, int l) {
  if constexpr (USE_WS) {
    return *(const f16x8*)(wsq + 110592 + (size_t)(kc * 12 + nt) * 512 + l * 8);
  } else {
    int n = nt * 16 + (l & 15), k = kc * 32 + (l >> 4) * 8;
    return cvt8(Wout + (size_t)n * 192 + k);
  }
}

// One block per 7x7 window, 512 threads = 8 waves. 3 barriers total.
template <bool USE_WS>
__global__ __launch_bounds__(512, 1) void wmsa_main(
    const float* __restrict__ x,
    const float* __restrict__ Wqkv,
    const float* __restrict__ bqkv,
    const float* __restrict__ relpos,
    const float* __restrict__ Wout,
    const float* __restrict__ bout,
    const f16* __restrict__ ws,
    float* __restrict__ out)
{
  __shared__ __align__(16) f16 s_x[1536 * 8];      // x -> attn out [64tok][24g]  24576 B
  __shared__ __align__(16) f16 s_qk[2 * 1536 * 8]; // q, k token-major            49152 B
  __shared__ __align__(16) f16 s_vT[1536 * 8];     // v^T [192ch][8g]             24576 B
  __shared__ __align__(16) f16 s_p[2 * 512 * 8];   // P [hg][64p][8g]             16384 B
  __shared__ float s_add[1014];                    // relpos + gaussian            4056 B

  const int tid = threadIdx.x;
  const int wi = blockIdx.x >> 6, wj = blockIdx.x & 63;
  const int wv = tid >> 6;
  const int l = tid & 63;
  const int l15 = l & 15, lg = l >> 4;
  const f32x4 zero4 = {0.f, 0.f, 0.f, 0.f};
  const float scale = 0.17677669529663687f;

  // ---------------- Phase 0: tables + rolled x window (f16, swizzled) -------
  for (int i = tid; i < 1014; i += 512) {
    int rem = i % 169;
    int di = rem / 13 - 6, dj = rem % 13 - 6;
    s_add[i] = relpos[i] + __expf((float)(di * di + dj * dj) * (-9.0f / 98.0f));
  }
  for (int gid = tid; gid < 1536; gid += 512) {
    int t = gid / 24, g = gid - t * 24;
    f16x8 v;
    if (t < 49) {
      int hh = wi * 7 + t / 7 + 3; if (hh >= 448) hh -= 448;
      int ww = wj * 7 + t % 7 + 3; if (ww >= 448) ww -= 448;
      v = cvt8(x + (size_t)(hh * 448 + ww) * 192 + g * 8);
    } else {
#pragma unroll
      for (int e = 0; e < 8; ++e) v[e] = (f16)0.0f;
    }
    *(f16x8*)&s_x[(t * 24 + (g ^ (t & 7))) * 8] = v;
  }
  __syncthreads();

  // ---------------- Phase 1: QKV. q/k swapped (W rows), v normal ------------
  {
    const int cq0 = wv * 3;          // qk ch-tile base (0..21), 24 tiles total
    const int cv0 = (wv >> 1) * 3;   // v ch-tile base (0..9), 12 tiles total
    const int tv0 = (wv & 1) * 2;    // v tok-tile base
    f32x4 aqk[3][4], av[3][2];
#pragma unroll
    for (int ci = 0; ci < 3; ++ci) {
#pragma unroll
      for (int t = 0; t < 4; ++t) aqk[ci][t] = zero4;
      av[ci][0] = zero4; av[ci][1] = zero4;
    }

#pragma unroll
    for (int kc = 0; kc < 6; ++kc) {
      f16x8 xf[4];
#pragma unroll
      for (int t = 0; t < 4; ++t) {
        int row = t * 16 + l15;
        xf[t] = *(const f16x8*)&s_x[(row * 24 + ((kc * 4 + lg) ^ (row & 7))) * 8];
      }
      f16x8 wq[3], wvf[3];
#pragma unroll
      for (int ci = 0; ci < 3; ++ci) {
        wq[ci]  = load_bq<USE_WS>(ws, Wqkv, kc, cq0 + ci, l);
        wvf[ci] = load_bq<USE_WS>(ws, Wqkv, kc, 24 + cv0 + ci, l);
      }
#pragma unroll
      for (int ci = 0; ci < 3; ++ci) {
#pragma unroll
        for (int t = 0; t < 4; ++t) aqk[ci][t] = MFMA16(wq[ci], xf[t], aqk[ci][t]);
#pragma unroll
        for (int tj = 0; tj < 2; ++tj)
          av[ci][tj] = MFMA16(xf[tv0 + tj], wvf[ci], av[ci][tj]);
      }
    }

    // epilogue: packed f16x4 writes. q gets the softmax scale folded in.
#pragma unroll
    for (int ci = 0; ci < 3; ++ci) {
      int c0 = (cq0 + ci) * 16 + lg * 4;          // 0..383
      float4 b4 = *(const float4*)(bqkv + c0);
      int part = (c0 >= 192) ? 1 : 0;
      int ch = c0 - part * 192;
      float mult = part ? 1.0f : scale;
#pragma unroll
      for (int t = 0; t < 4; ++t) {
        int tok = t * 16 + l15;
        f16x4 v;
        v[0] = (f16)((aqk[ci][t][0] + b4.x) * mult);
        v[1] = (f16)((aqk[ci][t][1] + b4.y) * mult);
        v[2] = (f16)((aqk[ci][t][2] + b4.z) * mult);
        v[3] = (f16)((aqk[ci][t][3] + b4.w) * mult);
        *(f16x4*)&s_qk[part * 12288 + (tok * 24 + ((ch >> 3) ^ (tok & 7))) * 8 + (ch & 7)] = v;
      }
      int vch = (cv0 + ci) * 16 + l15;            // 0..191
      float bv_ = bqkv[384 + vch];
#pragma unroll
      for (int tj = 0; tj < 2; ++tj) {
        int tok0 = (tv0 + tj) * 16 + lg * 4;
        f16x4 v;
#pragma unroll
        for (int r = 0; r < 4; ++r) v[r] = (f16)(av[ci][tj][r] + bv_);
        *(f16x4*)&s_vT[(vch * 8 + ((tok0 >> 3) ^ (vch & 7))) * 8 + (tok0 & 7)] = v;
      }
    }
  }
  __syncthreads();

  // ---------------- Phase 2: attention (S^T / O^T orientation) --------------
  {
    const int pt = wv & 3, hg = wv >> 2;
    const int p = 16 * pt + l15;
    const int pi = p / 7, pj = p - pi * 7;
    int moff[16];
    unsigned mbits = 0;
#pragma unroll
    for (int jq = 0; jq < 4; ++jq)
#pragma unroll
      for (int r = 0; r < 4; ++r) {
        int q = 16 * jq + lg * 4 + r;
        int qi = q / 7, qj = q - qi * 7;
        bool bad = (q >= 49) || (p >= 49) ||
                   ((wi == 63) && ((pi < 4) != (qi < 4))) ||
                   ((wj == 63) && ((pj < 4) != (qj < 4)));
        int idx = jq * 4 + r;
        moff[idx] = bad ? 0 : (pi - qi + 6) * 13 + (pj - qj + 6);
        if (bad) mbits |= (1u << idx);
      }

#pragma unroll
    for (int hh = 0; hh < 3; ++hh) {
      int h = hg * 3 + hh;
      // S^T = K · Q^T : lane holds col p, rows q = 16jq + lg*4 + r
      f16x8 aq = *(const f16x8*)&s_qk[(p * 24 + ((h * 4 + lg) ^ (p & 7))) * 8];
      f32x4 sc[4];
#pragma unroll
      for (int jq = 0; jq < 4; ++jq) {
        int krow = 16 * jq + l15;
        f16x8 bk = *(const f16x8*)&s_qk[12288 + (krow * 24 + ((h * 4 + lg) ^ (krow & 7))) * 8];
        sc[jq] = MFMA16(bk, aq, zero4);
      }
      float sv[16];
      float mx = -3.0e38f;
#pragma unroll
      for (int jq = 0; jq < 4; ++jq)
#pragma unroll
        for (int r = 0; r < 4; ++r) {
          int idx = jq * 4 + r;
          float s = (mbits >> idx & 1u) ? -1.0e30f
                                        : sc[jq][r] + s_add[h * 169 + moff[idx]];
          sv[idx] = s;
          mx = fmaxf(mx, s);
        }
      mx = fmaxf(mx, __shfl_xor(mx, 16));
      mx = fmaxf(mx, __shfl_xor(mx, 32));
      float sum = 0.0f;
#pragma unroll
      for (int i = 0; i < 16; ++i) {
        float e = __expf(sv[i] - mx);
        sv[i] = e;
        sum += e;
      }
      sum += __shfl_xor(sum, 16);
      sum += __shfl_xor(sum, 32);
      float inv = 1.0f / sum;
      // P store: packed f16x4 (4 consecutive q at fixed p)
#pragma unroll
      for (int jq = 0; jq < 4; ++jq) {
        int q0 = 16 * jq + lg * 4;
        f16x4 v;
#pragma unroll
        for (int r = 0; r < 4; ++r) v[r] = (f16)(sv[jq * 4 + r] * inv);
        *(f16x4*)&s_p[hg * 4096 + (p * 8 + ((q0 >> 3) ^ (p & 7))) * 8 + (q0 & 7)] = v;
      }
      // O^T = V^T · P^T : lane holds col p, rows = channels
      f32x4 o[2] = {zero4, zero4};
#pragma unroll
      for (int kq = 0; kq < 2; ++kq) {
        f16x8 ap = *(const f16x8*)&s_p[hg * 4096 + (p * 8 + ((kq * 4 + lg) ^ (p & 7))) * 8];
#pragma unroll
        for (int jn = 0; jn < 2; ++jn) {
          int ch = h * 32 + jn * 16 + l15;
          f16x8 bvv = *(const f16x8*)&s_vT[(ch * 8 + ((kq * 4 + lg) ^ (ch & 7))) * 8];
          o[jn] = MFMA16(bvv, ap, o[jn]);
        }
      }
#pragma unroll
      for (int jn = 0; jn < 2; ++jn) {
        int ch0 = h * 32 + jn * 16 + lg * 4;
        f16x4 v;
#pragma unroll
        for (int r = 0; r < 4; ++r) v[r] = (f16)o[jn][r];
        *(f16x4*)&s_x[(p * 24 + ((ch0 >> 3) ^ (p & 7))) * 8 + (ch0 & 7)] = v;
      }
    }
  }
  __syncthreads();

  // ---------------- Phase 3: out-proj (swapped) + packed float4 scatter -----
  {
    const int ct0 = (wv & 3) * 3;   // ch-tile base (0..9), 12 tiles total
    const int tg = wv >> 2;         // token-tile pair
    f32x4 acc3[3][2];
#pragma unroll
    for (int ci = 0; ci < 3; ++ci) { acc3[ci][0] = zero4; acc3[ci][1] = zero4; }

#pragma unroll
    for (int kc = 0; kc < 6; ++kc) {
      f16x8 bx[2];
#pragma unroll
      for (int tj = 0; tj < 2; ++tj) {
        int row = (tg * 2 + tj) * 16 + l15;
        bx[tj] = *(const f16x8*)&s_x[(row * 24 + ((kc * 4 + lg) ^ (row & 7))) * 8];
      }
#pragma unroll
      for (int ci = 0; ci < 3; ++ci) {
        f16x8 aw = load_bo<USE_WS>(ws, Wout, kc, ct0 + ci, l);
        acc3[ci][0] = MFMA16(aw, bx[0], acc3[ci][0]);
        acc3[ci][1] = MFMA16(aw, bx[1], acc3[ci][1]);
      }
    }

    const int rr = wi >> 4, w1i = wi & 15;
#pragma unroll
    for (int ci = 0; ci < 3; ++ci) {
      int ch0 = (ct0 + ci) * 16 + lg * 4;
      float4 b4 = *(const float4*)(bout + ch0);
#pragma unroll
      for (int tj = 0; tj < 2; ++tj) {
        int pp = (tg * 2 + tj) * 16 + l15;
        if (pp < 49) {
          int i2 = pp / 7, j2 = pp - i2 * 7;
          int y = w1i * 7 + i2 + 3;  if (y >= 112) y -= 112;
          int xc = wj * 7 + j2 + 3;  if (xc >= 448) xc -= 448;
          float4 st;
          st.x = acc3[ci][tj][0] + b4.x;
          st.y = acc3[ci][tj][1] + b4.y;
          st.z = acc3[ci][tj][2] + b4.z;
          st.w = acc3[ci][tj][3] + b4.w;
          *(float4*)(out + (size_t)(y * 448 + xc) * 768 + rr * 192 + ch0) = st;
        }
      }
    }
  }
}

extern "C" void kernel_launch(void* const* d_in, const int* in_sizes, int n_in,
                              void* d_out, int out_size, void* d_ws, size_t ws_size,
                              hipStream_t stream) {
  const float* x      = (const float*)d_in[0];
  const float* Wqkv   = (const float*)d_in[1];
  const float* bqkv   = (const float*)d_in[2];
  const float* relpos = (const float*)d_in[3];
  const float* Wout   = (const float*)d_in[4];
  const float* bout   = (const float*)d_in[5];
  float* out = (float*)d_out;
  f16* ws = (f16*)d_ws;

  if (ws_size >= (size_t)(110592 + 36864) * sizeof(f16)) {
    wmsa_prep<<<72, 256, 0, stream>>>(Wqkv, Wout, ws);
    wmsa_main<true><<<4096, 512, 0, stream>>>(x, Wqkv, bqkv, relpos, Wout, bout, ws, out);
  } else {
    wmsa_main<false><<<4096, 512, 0, stream>>>(x, Wqkv, bqkv, relpos, Wout, bout, ws, out);
  }
}

// Round 5
// 256.719 us; speedup vs baseline: 4.0881x; 4.0881x over previous
//
#include <hip/hip_runtime.h>

typedef _Float16 f16;
typedef _Float16 f16x8 __attribute__((ext_vector_type(8)));
typedef _Float16 f16x4 __attribute__((ext_vector_type(4)));
typedef float f32x4 __attribute__((ext_vector_type(4)));

#define MFMA16(a, b, c) __builtin_amdgcn_mfma_f32_16x16x32_f16(a, b, c, 0, 0, 0)

__device__ __forceinline__ f16x8 cvt8(const float* p) {
  const float4* s = (const float4*)p;
  float4 u0 = s[0], u1 = s[1];
  f16x8 v;
  v[0] = (f16)u0.x; v[1] = (f16)u0.y; v[2] = (f16)u0.z; v[3] = (f16)u0.w;
  v[4] = (f16)u1.x; v[5] = (f16)u1.y; v[6] = (f16)u1.z; v[7] = (f16)u1.w;
  return v;
}

// ---- prep: W_qkv / W_out -> f16 fragment-linear layout in ws ----
// frag (kc, nt, lane l): idx16 = nt*16 + (l&15), k = kc*32 + (l>>4)*8 .. +8
__global__ void wmsa_prep(const float* __restrict__ Wqkv,
                          const float* __restrict__ Wout,
                          f16* __restrict__ ws) {
  int gid = blockIdx.x * 256 + threadIdx.x;
  if (gid < 13824) {
    int fb = gid >> 6, l = gid & 63;
    int kc = fb / 36, nt = fb - kc * 36;
    int n = nt * 16 + (l & 15), k = kc * 32 + (l >> 4) * 8;
    *(f16x8*)(ws + (size_t)gid * 8) = cvt8(Wqkv + (size_t)n * 192 + k);
  } else if (gid < 18432) {
    int g2 = gid - 13824;
    int fb = g2 >> 6, l = g2 & 63;
    int kc = fb / 12, nt = fb - kc * 12;
    int n = nt * 16 + (l & 15), k = kc * 32 + (l >> 4) * 8;
    *(f16x8*)(ws + 110592 + (size_t)g2 * 8) = cvt8(Wout + (size_t)n * 192 + k);
  }
}

template <bool USE_WS>
__device__ __forceinline__ f16x8 load_bq(const f16* wsq, const float* Wqkv,
                                         int kc, int nt, int l) {
  if constexpr (USE_WS) {
    return *(const f16x8*)(wsq + (size_t)(kc * 36 + nt) * 512 + l * 8);
  } else {
    int n = nt * 16 + (l & 15), k = kc * 32 + (l >> 4) * 8;
    return cvt8(Wqkv + (size_t)n * 192 + k);
  }
}

template <bool USE_WS>
__device__ __forceinline__ f16x8 load_bo(const f16* wsq, const float* Wout,
                                         int kc, int nt, int l) {
  if constexpr (USE_WS) {
    return *(const f16x8*)(wsq + 110592 + (size_t)(kc * 12 + nt) * 512 + l * 8);
  } else {
    int n = nt * 16 + (l & 15), k = kc * 32 + (l >> 4) * 8;
    return cvt8(Wout + (size_t)n * 192 + k);
  }
}

// One block per 7x7 window, 512 threads = 8 waves. 3 barriers total.
template <bool USE_WS>
__global__ __launch_bounds__(512, 1) void wmsa_main(
    const float* __restrict__ x,
    const float* __restrict__ Wqkv,
    const float* __restrict__ bqkv,
    const float* __restrict__ relpos,
    const float* __restrict__ Wout,
    const float* __restrict__ bout,
    const f16* __restrict__ ws,
    float* __restrict__ out)
{
  __shared__ __align__(16) f16 s_x[1536 * 8];      // x -> attn out [64tok][24g]  24576 B
  __shared__ __align__(16) f16 s_qk[2 * 1536 * 8]; // q, k token-major            49152 B
  __shared__ __align__(16) f16 s_vT[1536 * 8];     // v^T [192ch][8g]             24576 B
  __shared__ __align__(16) f16 s_p[2 * 512 * 8];   // P [hg][64p][8g]             16384 B
  __shared__ float s_add[1014];                    // relpos + gaussian            4056 B

  const int tid = threadIdx.x;
  const int wi = blockIdx.x >> 6, wj = blockIdx.x & 63;
  const int wv = tid >> 6;
  const int l = tid & 63;
  const int l15 = l & 15, lg = l >> 4;
  const f32x4 zero4 = {0.f, 0.f, 0.f, 0.f};
  const float scale = 0.17677669529663687f;

  // ---------------- Phase 0: tables + rolled x window (f16, swizzled) -------
  for (int i = tid; i < 1014; i += 512) {
    int rem = i % 169;
    int di = rem / 13 - 6, dj = rem % 13 - 6;
    s_add[i] = relpos[i] + __expf((float)(di * di + dj * dj) * (-9.0f / 98.0f));
  }
  for (int gid = tid; gid < 1536; gid += 512) {
    int t = gid / 24, g = gid - t * 24;
    f16x8 v;
    if (t < 49) {
      int hh = wi * 7 + t / 7 + 3; if (hh >= 448) hh -= 448;
      int ww = wj * 7 + t % 7 + 3; if (ww >= 448) ww -= 448;
      v = cvt8(x + (size_t)(hh * 448 + ww) * 192 + g * 8);
    } else {
#pragma unroll
      for (int e = 0; e < 8; ++e) v[e] = (f16)0.0f;
    }
    *(f16x8*)&s_x[(t * 24 + (g ^ (t & 7))) * 8] = v;
  }
  __syncthreads();

  // ---------------- Phase 1: QKV. q/k swapped (W rows), v normal ------------
  {
    const int cq0 = wv * 3;          // qk ch-tile base (tiles 0..23)
    const int cv0 = (wv >> 1) * 3;   // v ch-tile base (tiles 0..11)
    const int tv0 = (wv & 1) * 2;    // v token-tile base (address use only!)
    f32x4 aqk[3][4], av[3][2];
#pragma unroll
    for (int ci = 0; ci < 3; ++ci) {
#pragma unroll
      for (int t = 0; t < 4; ++t) aqk[ci][t] = zero4;
      av[ci][0] = zero4; av[ci][1] = zero4;
    }

#pragma unroll
    for (int kc = 0; kc < 6; ++kc) {
      f16x8 xf[4];
#pragma unroll
      for (int t = 0; t < 4; ++t) {
        int row = t * 16 + l15;
        xf[t] = *(const f16x8*)&s_x[(row * 24 + ((kc * 4 + lg) ^ (row & 7))) * 8];
      }
      f16x8 wq[3], wvf[3];
#pragma unroll
      for (int ci = 0; ci < 3; ++ci) {
        wq[ci]  = load_bq<USE_WS>(ws, Wqkv, kc, cq0 + ci, l);
        wvf[ci] = load_bq<USE_WS>(ws, Wqkv, kc, 24 + cv0 + ci, l);
      }
#pragma unroll
      for (int ci = 0; ci < 3; ++ci)
#pragma unroll
        for (int t = 0; t < 4; ++t) aqk[ci][t] = MFMA16(wq[ci], xf[t], aqk[ci][t]);
      // v: compile-time fragment indices only (wave-uniform branch)
      if (wv & 1) {
#pragma unroll
        for (int ci = 0; ci < 3; ++ci) {
          av[ci][0] = MFMA16(xf[2], wvf[ci], av[ci][0]);
          av[ci][1] = MFMA16(xf[3], wvf[ci], av[ci][1]);
        }
      } else {
#pragma unroll
        for (int ci = 0; ci < 3; ++ci) {
          av[ci][0] = MFMA16(xf[0], wvf[ci], av[ci][0]);
          av[ci][1] = MFMA16(xf[1], wvf[ci], av[ci][1]);
        }
      }
    }

    // epilogue: packed f16x4 writes. q gets the softmax scale folded in.
#pragma unroll
    for (int ci = 0; ci < 3; ++ci) {
      int c0 = (cq0 + ci) * 16 + lg * 4;          // 0..383
      float4 b4 = *(const float4*)(bqkv + c0);
      int part = (c0 >= 192) ? 1 : 0;
      int ch = c0 - part * 192;
      float mult = part ? 1.0f : scale;
#pragma unroll
      for (int t = 0; t < 4; ++t) {
        int tok = t * 16 + l15;
        f16x4 v;
        v[0] = (f16)((aqk[ci][t][0] + b4.x) * mult);
        v[1] = (f16)((aqk[ci][t][1] + b4.y) * mult);
        v[2] = (f16)((aqk[ci][t][2] + b4.z) * mult);
        v[3] = (f16)((aqk[ci][t][3] + b4.w) * mult);
        *(f16x4*)&s_qk[part * 12288 + (tok * 24 + ((ch >> 3) ^ (tok & 7))) * 8 + (ch & 7)] = v;
      }
      int vch = (cv0 + ci) * 16 + l15;            // 0..191
      float bv_ = bqkv[384 + vch];
#pragma unroll
      for (int tj = 0; tj < 2; ++tj) {
        int tok0 = (tv0 + tj) * 16 + lg * 4;
        f16x4 v;
#pragma unroll
        for (int r = 0; r < 4; ++r) v[r] = (f16)(av[ci][tj][r] + bv_);
        *(f16x4*)&s_vT[(vch * 8 + ((tok0 >> 3) ^ (vch & 7))) * 8 + (tok0 & 7)] = v;
      }
    }
  }
  __syncthreads();

  // ---------------- Phase 2: attention (S^T / O^T orientation) --------------
  {
    const int pt = wv & 3, hg = wv >> 2;
    const int p = 16 * pt + l15;
    const int pi = p / 7, pj = p - pi * 7;
    int moff[16];
    unsigned mbits = 0;
#pragma unroll
    for (int jq = 0; jq < 4; ++jq)
#pragma unroll
      for (int r = 0; r < 4; ++r) {
        int q = 16 * jq + lg * 4 + r;
        int qi = q / 7, qj = q - qi * 7;
        bool bad = (q >= 49) || (p >= 49) ||
                   ((wi == 63) && ((pi < 4) != (qi < 4))) ||
                   ((wj == 63) && ((pj < 4) != (qj < 4)));
        int idx = jq * 4 + r;
        moff[idx] = bad ? 0 : (pi - qi + 6) * 13 + (pj - qj + 6);
        if (bad) mbits |= (1u << idx);
      }

#pragma unroll
    for (int hh = 0; hh < 3; ++hh) {
      int h = hg * 3 + hh;
      // S^T = K · Q^T : lane holds col p, rows q = 16jq + lg*4 + r
      f16x8 aq = *(const f16x8*)&s_qk[(p * 24 + ((h * 4 + lg) ^ (p & 7))) * 8];
      f32x4 sc[4];
#pragma unroll
      for (int jq = 0; jq < 4; ++jq) {
        int krow = 16 * jq + l15;
        f16x8 bk = *(const f16x8*)&s_qk[12288 + (krow * 24 + ((h * 4 + lg) ^ (krow & 7))) * 8];
        sc[jq] = MFMA16(bk, aq, zero4);
      }
      float sv[16];
      float mx = -3.0e38f;
#pragma unroll
      for (int jq = 0; jq < 4; ++jq)
#pragma unroll
        for (int r = 0; r < 4; ++r) {
          int idx = jq * 4 + r;
          float s = (mbits >> idx & 1u) ? -1.0e30f
                                        : sc[jq][r] + s_add[h * 169 + moff[idx]];
          sv[idx] = s;
          mx = fmaxf(mx, s);
        }
      mx = fmaxf(mx, __shfl_xor(mx, 16));
      mx = fmaxf(mx, __shfl_xor(mx, 32));
      float sum = 0.0f;
#pragma unroll
      for (int i = 0; i < 16; ++i) {
        float e = __expf(sv[i] - mx);
        sv[i] = e;
        sum += e;
      }
      sum += __shfl_xor(sum, 16);
      sum += __shfl_xor(sum, 32);
      float inv = 1.0f / sum;
      // P store: packed f16x4 (4 consecutive q at fixed p)
#pragma unroll
      for (int jq = 0; jq < 4; ++jq) {
        int q0 = 16 * jq + lg * 4;
        f16x4 v;
#pragma unroll
        for (int r = 0; r < 4; ++r) v[r] = (f16)(sv[jq * 4 + r] * inv);
        *(f16x4*)&s_p[hg * 4096 + (p * 8 + ((q0 >> 3) ^ (p & 7))) * 8 + (q0 & 7)] = v;
      }
      // O^T = V^T · P^T : lane holds col p, rows = channels
      f32x4 o[2] = {zero4, zero4};
#pragma unroll
      for (int kq = 0; kq < 2; ++kq) {
        f16x8 ap = *(const f16x8*)&s_p[hg * 4096 + (p * 8 + ((kq * 4 + lg) ^ (p & 7))) * 8];
#pragma unroll
        for (int jn = 0; jn < 2; ++jn) {
          int ch = h * 32 + jn * 16 + l15;
          f16x8 bvv = *(const f16x8*)&s_vT[(ch * 8 + ((kq * 4 + lg) ^ (ch & 7))) * 8];
          o[jn] = MFMA16(bvv, ap, o[jn]);
        }
      }
#pragma unroll
      for (int jn = 0; jn < 2; ++jn) {
        int ch0 = h * 32 + jn * 16 + lg * 4;
        f16x4 v;
#pragma unroll
        for (int r = 0; r < 4; ++r) v[r] = (f16)o[jn][r];
        *(f16x4*)&s_x[(p * 24 + ((ch0 >> 3) ^ (p & 7))) * 8 + (ch0 & 7)] = v;
      }
    }
  }
  __syncthreads();

  // ---------------- Phase 3: out-proj (non-swapped, coalesced stores) -------
  {
    const int mp = wv >> 2, q3 = wv & 3;
    f32x4 acc3[2][3];
#pragma unroll
    for (int m = 0; m < 2; ++m)
#pragma unroll
      for (int j = 0; j < 3; ++j) acc3[m][j] = zero4;

#pragma unroll
    for (int kc = 0; kc < 6; ++kc) {
      f16x8 b[3];
#pragma unroll
      for (int j = 0; j < 3; ++j) b[j] = load_bo<USE_WS>(ws, Wout, kc, 3 * q3 + j, l);
      f16x8 a[2];
#pragma unroll
      for (int m = 0; m < 2; ++m) {
        int row = 32 * mp + 16 * m + l15;
        a[m] = *(const f16x8*)&s_x[(row * 24 + ((kc * 4 + lg) ^ (row & 7))) * 8];
      }
#pragma unroll
      for (int j = 0; j < 3; ++j) {
        acc3[0][j] = MFMA16(a[0], b[j], acc3[0][j]);
        acc3[1][j] = MFMA16(a[1], b[j], acc3[1][j]);
      }
    }

    const int rr = wi >> 4, w1i = wi & 15;
#pragma unroll
    for (int j = 0; j < 3; ++j) {
      int c = (3 * q3 + j) * 16 + l15;
      float bias = bout[c];
#pragma unroll
      for (int m = 0; m < 2; ++m) {
#pragma unroll
        for (int r = 0; r < 4; ++r) {
          int pp = 32 * mp + 16 * m + lg * 4 + r;
          if (pp < 49) {
            int i2 = pp / 7, j2 = pp - i2 * 7;
            int y = w1i * 7 + i2 + 3;  if (y >= 112) y -= 112;
            int xc = wj * 7 + j2 + 3;  if (xc >= 448) xc -= 448;
            out[(size_t)(y * 448 + xc) * 768 + rr * 192 + c] = acc3[m][j][r] + bias;
          }
        }
      }
    }
  }
}

extern "C" void kernel_launch(void* const* d_in, const int* in_sizes, int n_in,
                              void* d_out, int out_size, void* d_ws, size_t ws_size,
                              hipStream_t stream) {
  const float* x      = (const float*)d_in[0];
  const float* Wqkv   = (const float*)d_in[1];
  const float* bqkv   = (const float*)d_in[2];
  const float* relpos = (const float*)d_in[3];
  const float* Wout   = (const float*)d_in[4];
  const float* bout   = (const float*)d_in[5];
  float* out = (float*)d_out;
  f16* ws = (f16*)d_ws;

  if (ws_size >= (size_t)(110592 + 36864) * sizeof(f16)) {
    wmsa_prep<<<72, 256, 0, stream>>>(Wqkv, Wout, ws);
    wmsa_main<true><<<4096, 512, 0, stream>>>(x, Wqkv, bqkv, relpos, Wout, bout, ws, out);
  } else {
    wmsa_main<false><<<4096, 512, 0, stream>>>(x, Wqkv, bqkv, relpos, Wout, bout, ws, out);
  }
}

// Round 6
// 241.830 us; speedup vs baseline: 4.3398x; 1.0616x over previous
//
#include <hip/hip_runtime.h>

typedef _Float16 f16;
typedef _Float16 f16x8 __attribute__((ext_vector_type(8)));
typedef _Float16 f16x4 __attribute__((ext_vector_type(4)));
typedef float f32x4 __attribute__((ext_vector_type(4)));

#define MFMA16(a, b, c) __builtin_amdgcn_mfma_f32_16x16x32_f16(a, b, c, 0, 0, 0)

__device__ __forceinline__ f16x8 cvt8(const float* p) {
  const float4* s = (const float4*)p;
  float4 u0 = s[0], u1 = s[1];
  f16x8 v;
  v[0] = (f16)u0.x; v[1] = (f16)u0.y; v[2] = (f16)u0.z; v[3] = (f16)u0.w;
  v[4] = (f16)u1.x; v[5] = (f16)u1.y; v[6] = (f16)u1.z; v[7] = (f16)u1.w;
  return v;
}

// ---- prep: W_qkv / W_out -> f16 fragment-linear layout in ws ----
// frag (kc, nt, lane l): idx16 = nt*16 + (l&15), k = kc*32 + (l>>4)*8 .. +8
__global__ void wmsa_prep(const float* __restrict__ Wqkv,
                          const float* __restrict__ Wout,
                          f16* __restrict__ ws) {
  int gid = blockIdx.x * 256 + threadIdx.x;
  if (gid < 13824) {
    int fb = gid >> 6, l = gid & 63;
    int kc = fb / 36, nt = fb - kc * 36;
    int n = nt * 16 + (l & 15), k = kc * 32 + (l >> 4) * 8;
    *(f16x8*)(ws + (size_t)gid * 8) = cvt8(Wqkv + (size_t)n * 192 + k);
  } else if (gid < 18432) {
    int g2 = gid - 13824;
    int fb = g2 >> 6, l = g2 & 63;
    int kc = fb / 12, nt = fb - kc * 12;
    int n = nt * 16 + (l & 15), k = kc * 32 + (l >> 4) * 8;
    *(f16x8*)(ws + 110592 + (size_t)g2 * 8) = cvt8(Wout + (size_t)n * 192 + k);
  }
}

template <bool USE_WS>
__device__ __forceinline__ f16x8 load_bq(const f16* wsq, const float* Wqkv,
                                         int kc, int nt, int l) {
  if constexpr (USE_WS) {
    return *(const f16x8*)(wsq + (size_t)(kc * 36 + nt) * 512 + l * 8);
  } else {
    int n = nt * 16 + (l & 15), k = kc * 32 + (l >> 4) * 8;
    return cvt8(Wqkv + (size_t)n * 192 + k);
  }
}

template <bool USE_WS>
__device__ __forceinline__ f16x8 load_bo(const f16* wsq, const float* Wout,
                                         int kc, int nt, int l) {
  if constexpr (USE_WS) {
    return *(const f16x8*)(wsq + 110592 + (size_t)(kc * 12 + nt) * 512 + l * 8);
  } else {
    int n = nt * 16 + (l & 15), k = kc * 32 + (l >> 4) * 8;
    return cvt8(Wout + (size_t)n * 192 + k);
  }
}

// One block per 7x7 window, 1024 threads = 16 waves = 4 waves/SIMD.
// 3 barriers total.
template <bool USE_WS>
__global__ __launch_bounds__(1024, 1) void wmsa_main(
    const float* __restrict__ x,
    const float* __restrict__ Wqkv,
    const float* __restrict__ bqkv,
    const float* __restrict__ relpos,
    const float* __restrict__ Wout,
    const float* __restrict__ bout,
    const f16* __restrict__ ws,
    float* __restrict__ out)
{
  __shared__ __align__(16) f16 s_x[1536 * 8];      // x -> attn out [64tok][24g]  24576 B
  __shared__ __align__(16) f16 s_qk[2 * 1536 * 8]; // q, k token-major            49152 B
  __shared__ __align__(16) f16 s_vT[1536 * 8];     // v^T [192ch][8g]             24576 B
  __shared__ __align__(16) f16 s_p[4 * 512 * 8];   // P [hi][64p][8g]             32768 B
  __shared__ float s_add[1014];                    // relpos + gaussian            4056 B

  const int tid = threadIdx.x;
  const int wi = blockIdx.x >> 6, wj = blockIdx.x & 63;
  const int wv = tid >> 6;
  const int l = tid & 63;
  const int l15 = l & 15, lg = l >> 4;
  const f32x4 zero4 = {0.f, 0.f, 0.f, 0.f};
  const float scale = 0.17677669529663687f;

  // ---------------- Phase 0: tables + rolled x window (f16, swizzled) -------
  for (int i = tid; i < 1014; i += 1024) {
    int rem = i % 169;
    int di = rem / 13 - 6, dj = rem % 13 - 6;
    s_add[i] = relpos[i] + __expf((float)(di * di + dj * dj) * (-9.0f / 98.0f));
  }
  for (int gid = tid; gid < 1536; gid += 1024) {
    int t = gid / 24, g = gid - t * 24;
    f16x8 v;
    if (t < 49) {
      int hh = wi * 7 + t / 7 + 3; if (hh >= 448) hh -= 448;
      int ww = wj * 7 + t % 7 + 3; if (ww >= 448) ww -= 448;
      v = cvt8(x + (size_t)(hh * 448 + ww) * 192 + g * 8);
    } else {
#pragma unroll
      for (int e = 0; e < 8; ++e) v[e] = (f16)0.0f;
    }
    *(f16x8*)&s_x[(t * 24 + (g ^ (t & 7))) * 8] = v;
  }
  __syncthreads();

  // ---------------- Phase 1: QKV. waves 0-11: q/k (swapped); 12-15: v -------
  if (wv < 12) {
    // q/k: wave handles ch-tiles {2wv, 2wv+1} x 4 token tiles
    f32x4 aqk[2][4];
#pragma unroll
    for (int ci = 0; ci < 2; ++ci)
#pragma unroll
      for (int t = 0; t < 4; ++t) aqk[ci][t] = zero4;

#pragma unroll
    for (int kc = 0; kc < 6; ++kc) {
      f16x8 xf[4];
#pragma unroll
      for (int t = 0; t < 4; ++t) {
        int row = t * 16 + l15;
        xf[t] = *(const f16x8*)&s_x[(row * 24 + ((kc * 4 + lg) ^ (row & 7))) * 8];
      }
      f16x8 wq[2];
#pragma unroll
      for (int ci = 0; ci < 2; ++ci)
        wq[ci] = load_bq<USE_WS>(ws, Wqkv, kc, 2 * wv + ci, l);
#pragma unroll
      for (int ci = 0; ci < 2; ++ci)
#pragma unroll
        for (int t = 0; t < 4; ++t) aqk[ci][t] = MFMA16(wq[ci], xf[t], aqk[ci][t]);
    }

    // epilogue: packed f16x4 writes, softmax scale folded into q
#pragma unroll
    for (int ci = 0; ci < 2; ++ci) {
      int c0 = (2 * wv + ci) * 16 + lg * 4;       // 0..383
      float4 b4 = *(const float4*)(bqkv + c0);
      int part = (c0 >= 192) ? 1 : 0;
      int ch = c0 - part * 192;
      float mult = part ? 1.0f : scale;
#pragma unroll
      for (int t = 0; t < 4; ++t) {
        int tok = t * 16 + l15;
        f16x4 v;
        v[0] = (f16)((aqk[ci][t][0] + b4.x) * mult);
        v[1] = (f16)((aqk[ci][t][1] + b4.y) * mult);
        v[2] = (f16)((aqk[ci][t][2] + b4.z) * mult);
        v[3] = (f16)((aqk[ci][t][3] + b4.w) * mult);
        *(f16x4*)&s_qk[part * 12288 + (tok * 24 + ((ch >> 3) ^ (tok & 7))) * 8 + (ch & 7)] = v;
      }
    }
  } else {
    // v: wave handles ch-tiles {3(wv-12)..+3} x 4 token tiles, normal orient.
    const int cv0 = (wv - 12) * 3;
    f32x4 av[3][4];
#pragma unroll
    for (int ci = 0; ci < 3; ++ci)
#pragma unroll
      for (int t = 0; t < 4; ++t) av[ci][t] = zero4;

#pragma unroll
    for (int kc = 0; kc < 6; ++kc) {
      f16x8 xf[4];
#pragma unroll
      for (int t = 0; t < 4; ++t) {
        int row = t * 16 + l15;
        xf[t] = *(const f16x8*)&s_x[(row * 24 + ((kc * 4 + lg) ^ (row & 7))) * 8];
      }
      f16x8 wvf[3];
#pragma unroll
      for (int ci = 0; ci < 3; ++ci)
        wvf[ci] = load_bq<USE_WS>(ws, Wqkv, kc, 24 + cv0 + ci, l);
#pragma unroll
      for (int ci = 0; ci < 3; ++ci)
#pragma unroll
        for (int t = 0; t < 4; ++t) av[ci][t] = MFMA16(xf[t], wvf[ci], av[ci][t]);
    }

#pragma unroll
    for (int ci = 0; ci < 3; ++ci) {
      int vch = (cv0 + ci) * 16 + l15;            // 0..191
      float bv_ = bqkv[384 + vch];
#pragma unroll
      for (int t = 0; t < 4; ++t) {
        int tok0 = t * 16 + lg * 4;
        f16x4 v;
#pragma unroll
        for (int r = 0; r < 4; ++r) v[r] = (f16)(av[ci][t][r] + bv_);
        *(f16x4*)&s_vT[(vch * 8 + ((tok0 >> 3) ^ (vch & 7))) * 8 + (tok0 & 7)] = v;
      }
    }
  }
  __syncthreads();

  // ---------------- Phase 2: attention (S^T / O^T orientation) --------------
  {
    const int pt = wv & 3, hi = wv >> 2;
    const int h_first = (hi < 2) ? (hi * 2) : (hi + 2);   // 0,2,4,5
    const int h_count = (hi < 2) ? 2 : 1;
    const int p = 16 * pt + l15;
    const int pi = p / 7, pj = p - pi * 7;
    int moff[16];
    unsigned mbits = 0;
#pragma unroll
    for (int jq = 0; jq < 4; ++jq)
#pragma unroll
      for (int r = 0; r < 4; ++r) {
        int q = 16 * jq + lg * 4 + r;
        int qi = q / 7, qj = q - qi * 7;
        bool bad = (q >= 49) || (p >= 49) ||
                   ((wi == 63) && ((pi < 4) != (qi < 4))) ||
                   ((wj == 63) && ((pj < 4) != (qj < 4)));
        int idx = jq * 4 + r;
        moff[idx] = bad ? 0 : (pi - qi + 6) * 13 + (pj - qj + 6);
        if (bad) mbits |= (1u << idx);
      }

    for (int e = 0; e < h_count; ++e) {
      int h = h_first + e;
      // S^T = K · Q^T : lane holds col p, rows q = 16jq + lg*4 + r
      f16x8 aq = *(const f16x8*)&s_qk[(p * 24 + ((h * 4 + lg) ^ (p & 7))) * 8];
      f32x4 sc[4];
#pragma unroll
      for (int jq = 0; jq < 4; ++jq) {
        int krow = 16 * jq + l15;
        f16x8 bk = *(const f16x8*)&s_qk[12288 + (krow * 24 + ((h * 4 + lg) ^ (krow & 7))) * 8];
        sc[jq] = MFMA16(bk, aq, zero4);
      }
      float sv[16];
      float mx = -3.0e38f;
#pragma unroll
      for (int jq = 0; jq < 4; ++jq)
#pragma unroll
        for (int r = 0; r < 4; ++r) {
          int idx = jq * 4 + r;
          float s = (mbits >> idx & 1u) ? -1.0e30f
                                        : sc[jq][r] + s_add[h * 169 + moff[idx]];
          sv[idx] = s;
          mx = fmaxf(mx, s);
        }
      mx = fmaxf(mx, __shfl_xor(mx, 16));
      mx = fmaxf(mx, __shfl_xor(mx, 32));
      float sum = 0.0f;
#pragma unroll
      for (int i = 0; i < 16; ++i) {
        float ev = __expf(sv[i] - mx);
        sv[i] = ev;
        sum += ev;
      }
      sum += __shfl_xor(sum, 16);
      sum += __shfl_xor(sum, 32);
      float inv = 1.0f / sum;
      // P store: packed f16x4 (region private to this wave: (hi, p-rows))
#pragma unroll
      for (int jq = 0; jq < 4; ++jq) {
        int q0 = 16 * jq + lg * 4;
        f16x4 v;
#pragma unroll
        for (int r = 0; r < 4; ++r) v[r] = (f16)(sv[jq * 4 + r] * inv);
        *(f16x4*)&s_p[hi * 4096 + (p * 8 + ((q0 >> 3) ^ (p & 7))) * 8 + (q0 & 7)] = v;
      }
      // O^T = V^T · P^T : lane holds col p, rows = channels
      f32x4 o[2] = {zero4, zero4};
#pragma unroll
      for (int kq = 0; kq < 2; ++kq) {
        f16x8 ap = *(const f16x8*)&s_p[hi * 4096 + (p * 8 + ((kq * 4 + lg) ^ (p & 7))) * 8];
#pragma unroll
        for (int jn = 0; jn < 2; ++jn) {
          int ch = h * 32 + jn * 16 + l15;
          f16x8 bvv = *(const f16x8*)&s_vT[(ch * 8 + ((kq * 4 + lg) ^ (ch & 7))) * 8];
          o[jn] = MFMA16(bvv, ap, o[jn]);
        }
      }
#pragma unroll
      for (int jn = 0; jn < 2; ++jn) {
        int ch0 = h * 32 + jn * 16 + lg * 4;
        f16x4 v;
#pragma unroll
        for (int r = 0; r < 4; ++r) v[r] = (f16)o[jn][r];
        *(f16x4*)&s_x[(p * 24 + ((ch0 >> 3) ^ (p & 7))) * 8 + (ch0 & 7)] = v;
      }
    }
  }
  __syncthreads();

  // ---------------- Phase 3: out-proj (non-swapped, coalesced stores) -------
  {
    const int tt = wv >> 2, cg = wv & 3;   // token-tile, ch-group (3 tiles)
    f32x4 acc3[3];
#pragma unroll
    for (int j = 0; j < 3; ++j) acc3[j] = zero4;

#pragma unroll
    for (int kc = 0; kc < 6; ++kc) {
      f16x8 b[3];
#pragma unroll
      for (int j = 0; j < 3; ++j) b[j] = load_bo<USE_WS>(ws, Wout, kc, 3 * cg + j, l);
      int row = tt * 16 + l15;
      f16x8 a = *(const f16x8*)&s_x[(row * 24 + ((kc * 4 + lg) ^ (row & 7))) * 8];
#pragma unroll
      for (int j = 0; j < 3; ++j) acc3[j] = MFMA16(a, b[j], acc3[j]);
    }

    const int rr = wi >> 4, w1i = wi & 15;
#pragma unroll
    for (int j = 0; j < 3; ++j) {
      int c = (3 * cg + j) * 16 + l15;
      float bias = bout[c];
#pragma unroll
      for (int r = 0; r < 4; ++r) {
        int pp = tt * 16 + lg * 4 + r;
        if (pp < 49) {
          int i2 = pp / 7, j2 = pp - i2 * 7;
          int y = w1i * 7 + i2 + 3;  if (y >= 112) y -= 112;
          int xc = wj * 7 + j2 + 3;  if (xc >= 448) xc -= 448;
          out[(size_t)(y * 448 + xc) * 768 + rr * 192 + c] = acc3[j][r] + bias;
        }
      }
    }
  }
}

extern "C" void kernel_launch(void* const* d_in, const int* in_sizes, int n_in,
                              void* d_out, int out_size, void* d_ws, size_t ws_size,
                              hipStream_t stream) {
  const float* x      = (const float*)d_in[0];
  const float* Wqkv   = (const float*)d_in[1];
  const float* bqkv   = (const float*)d_in[2];
  const float* relpos = (const float*)d_in[3];
  const float* Wout   = (const float*)d_in[4];
  const float* bout   = (const float*)d_in[5];
  float* out = (float*)d_out;
  f16* ws = (f16*)d_ws;

  if (ws_size >= (size_t)(110592 + 36864) * sizeof(f16)) {
    wmsa_prep<<<72, 256, 0, stream>>>(Wqkv, Wout, ws);
    wmsa_main<true><<<4096, 1024, 0, stream>>>(x, Wqkv, bqkv, relpos, Wout, bout, ws, out);
  } else {
    wmsa_main<false><<<4096, 1024, 0, stream>>>(x, Wqkv, bqkv, relpos, Wout, bout, ws, out);
  }
}

// Round 8
// 199.555 us; speedup vs baseline: 5.2591x; 1.2118x over previous
//
#include <hip/hip_runtime.h>

typedef _Float16 f16;
typedef _Float16 f16x8 __attribute__((ext_vector_type(8)));
typedef _Float16 f16x4 __attribute__((ext_vector_type(4)));
typedef _Float16 f16x2 __attribute__((ext_vector_type(2)));
typedef float f32x4 __attribute__((ext_vector_type(4)));

#define MFMA16(a, b, c) __builtin_amdgcn_mfma_f32_16x16x32_f16(a, b, c, 0, 0, 0)

__device__ __forceinline__ f16x2 pkcvt(float a, float b) {
  auto r = __builtin_amdgcn_cvt_pkrtz(a, b);   // __fp16 ext_vector(2)
  union { decltype(r) i; f16x2 o; } u;
  u.i = r;
  return u.o;
}

__device__ __forceinline__ f16x4 pk4(float a, float b, float c, float d) {
  union { f16x2 h2[2]; f16x4 h4; } u;
  u.h2[0] = pkcvt(a, b);
  u.h2[1] = pkcvt(c, d);
  return u.h4;
}

// RTZ packed convert of 8 consecutive f32 (main kernel hot path)
__device__ __forceinline__ f16x8 cvt8z(const float* p) {
  const float4* s = (const float4*)p;
  float4 u0 = s[0], u1 = s[1];
  union { f16x2 h2[4]; f16x8 h8; } u;
  u.h2[0] = pkcvt(u0.x, u0.y);
  u.h2[1] = pkcvt(u0.z, u0.w);
  u.h2[2] = pkcvt(u1.x, u1.y);
  u.h2[3] = pkcvt(u1.z, u1.w);
  return u.h8;
}

// RTE convert (prep kernel / fallback path — accuracy-first)
__device__ __forceinline__ f16x8 cvt8(const float* p) {
  const float4* s = (const float4*)p;
  float4 u0 = s[0], u1 = s[1];
  f16x8 v;
  v[0] = (f16)u0.x; v[1] = (f16)u0.y; v[2] = (f16)u0.z; v[3] = (f16)u0.w;
  v[4] = (f16)u1.x; v[5] = (f16)u1.y; v[6] = (f16)u1.z; v[7] = (f16)u1.w;
  return v;
}

// ---- prep: W_qkv / W_out -> f16 fragment-linear layout in ws (RTE) ----
// frag (kc, nt, lane l): n = nt*16 + (l&15), k = kc*32 + (l>>4)*8 .. +8
__global__ void wmsa_prep(const float* __restrict__ Wqkv,
                          const float* __restrict__ Wout,
                          f16* __restrict__ ws) {
  int gid = blockIdx.x * 256 + threadIdx.x;
  if (gid < 13824) {
    int fb = gid >> 6, l = gid & 63;
    int kc = fb / 36, nt = fb - kc * 36;
    int n = nt * 16 + (l & 15), k = kc * 32 + (l >> 4) * 8;
    *(f16x8*)(ws + (size_t)gid * 8) = cvt8(Wqkv + (size_t)n * 192 + k);
  } else if (gid < 18432) {
    int g2 = gid - 13824;
    int fb = g2 >> 6, l = g2 & 63;
    int kc = fb / 12, nt = fb - kc * 12;
    int n = nt * 16 + (l & 15), k = kc * 32 + (l >> 4) * 8;
    *(f16x8*)(ws + 110592 + (size_t)g2 * 8) = cvt8(Wout + (size_t)n * 192 + k);
  }
}

template <bool USE_WS>
__device__ __forceinline__ f16x8 load_bq(const f16* wsq, const float* Wqkv,
                                         int kc, int nt, int l) {
  if constexpr (USE_WS) {
    return *(const f16x8*)(wsq + (size_t)(kc * 36 + nt) * 512 + l * 8);
  } else {
    int n = nt * 16 + (l & 15), k = kc * 32 + (l >> 4) * 8;
    return cvt8(Wqkv + (size_t)n * 192 + k);
  }
}

template <bool USE_WS>
__device__ __forceinline__ f16x8 load_bo(const f16* wsq, const float* Wout,
                                         int kc, int nt, int l) {
  if constexpr (USE_WS) {
    return *(const f16x8*)(wsq + 110592 + (size_t)(kc * 12 + nt) * 512 + l * 8);
  } else {
    int n = nt * 16 + (l & 15), k = kc * 32 + (l >> 4) * 8;
    return cvt8(Wout + (size_t)n * 192 + k);
  }
}

// One block per 7x7 window, 1024 threads = 16 waves = 4 waves/SIMD.
// Padded-stride LDS layouts (rows stride 25 / 9 granules -> <=2-way conflicts).
template <bool USE_WS>
__global__ __launch_bounds__(1024, 1) void wmsa_main(
    const float* __restrict__ x,
    const float* __restrict__ Wqkv,
    const float* __restrict__ bqkv,
    const float* __restrict__ relpos,
    const float* __restrict__ Wout,
    const float* __restrict__ bout,
    const f16* __restrict__ ws,
    float* __restrict__ out)
{
  __shared__ __align__(16) f16 s_x[1600 * 8];   // [64 tok][25g]           25600 B
  __shared__ __align__(16) f16 s_qk[3200 * 8];  // q,k: 2 x [64 tok][25g]  51200 B
  __shared__ __align__(16) f16 s_vT[1728 * 8];  // v^T [192 ch][9g]        27648 B
  __shared__ __align__(16) f16 s_p[2304 * 8];   // P [4 hi][64 p][9g]      36864 B
  __shared__ float s_add[1014];                 // (relpos+gauss)*log2e     4056 B

  const int tid = threadIdx.x;
  const int wi = blockIdx.x >> 6, wj = blockIdx.x & 63;
  const int wv = tid >> 6;
  const int l = tid & 63;
  const int l15 = l & 15, lg = l >> 4;
  const f32x4 zero4 = {0.f, 0.f, 0.f, 0.f};
  const float QMULT = 0.17677669529663687f * 1.4426950408889634f; // scale*log2e

  // ---------------- Phase 0: tables + rolled x window (f16) ----------------
  for (int i = tid; i < 1014; i += 1024) {
    int rem = i % 169;
    int di = rem / 13 - 6, dj = rem % 13 - 6;
    s_add[i] = (relpos[i] + __expf((float)(di * di + dj * dj) * (-9.0f / 98.0f)))
               * 1.4426950408889634f;
  }
  for (int gid = tid; gid < 1536; gid += 1024) {
    int t = gid / 24, g = gid - t * 24;
    f16x8 v;
    if (t < 49) {
      int hh = wi * 7 + t / 7 + 3; if (hh >= 448) hh -= 448;
      int ww = wj * 7 + t % 7 + 3; if (ww >= 448) ww -= 448;
      v = cvt8z(x + (size_t)(hh * 448 + ww) * 192 + g * 8);
    } else {
#pragma unroll
      for (int e = 0; e < 8; ++e) v[e] = (f16)0.0f;
    }
    *(f16x8*)&s_x[(t * 25 + g) * 8] = v;
  }
  __syncthreads();

  // ---------------- Phase 1: QKV. waves 0-11: q/k (swapped); 12-15: v -------
  if (wv < 12) {
    f32x4 aqk[2][4];
#pragma unroll
    for (int ci = 0; ci < 2; ++ci)
#pragma unroll
      for (int t = 0; t < 4; ++t) aqk[ci][t] = zero4;

#pragma unroll
    for (int kc = 0; kc < 6; ++kc) {
      f16x8 xf[4];
#pragma unroll
      for (int t = 0; t < 4; ++t)
        xf[t] = *(const f16x8*)&s_x[((t * 16 + l15) * 25 + kc * 4 + lg) * 8];
      f16x8 wq0 = load_bq<USE_WS>(ws, Wqkv, kc, 2 * wv, l);
      f16x8 wq1 = load_bq<USE_WS>(ws, Wqkv, kc, 2 * wv + 1, l);
#pragma unroll
      for (int t = 0; t < 4; ++t) aqk[0][t] = MFMA16(wq0, xf[t], aqk[0][t]);
#pragma unroll
      for (int t = 0; t < 4; ++t) aqk[1][t] = MFMA16(wq1, xf[t], aqk[1][t]);
    }

    // epilogue: packed f16x4 writes; softmax scale*log2e folded into q
#pragma unroll
    for (int ci = 0; ci < 2; ++ci) {
      int c0 = (2 * wv + ci) * 16 + lg * 4;       // 0..383
      float4 b4 = *(const float4*)(bqkv + c0);
      int part = (c0 >= 192) ? 1 : 0;
      int ch = c0 - part * 192;
      float mult = part ? 1.0f : QMULT;
      float bx = b4.x * mult, by = b4.y * mult, bz = b4.z * mult, bw = b4.w * mult;
      int gbase = part * 1600 + (ch >> 3);
      int sub = ch & 7;
#pragma unroll
      for (int t = 0; t < 4; ++t) {
        int tok = t * 16 + l15;
        f16x4 v = pk4(fmaf(aqk[ci][t][0], mult, bx), fmaf(aqk[ci][t][1], mult, by),
                      fmaf(aqk[ci][t][2], mult, bz), fmaf(aqk[ci][t][3], mult, bw));
        *(f16x4*)&s_qk[(gbase + tok * 25) * 8 + sub] = v;
      }
    }
  } else {
    const int cv0 = (wv - 12) * 3;
    f32x4 av[3][4];
#pragma unroll
    for (int ci = 0; ci < 3; ++ci)
#pragma unroll
      for (int t = 0; t < 4; ++t) av[ci][t] = zero4;

#pragma unroll
    for (int kc = 0; kc < 6; ++kc) {
      f16x8 xf[4];
#pragma unroll
      for (int t = 0; t < 4; ++t)
        xf[t] = *(const f16x8*)&s_x[((t * 16 + l15) * 25 + kc * 4 + lg) * 8];
      f16x8 w0 = load_bq<USE_WS>(ws, Wqkv, kc, 24 + cv0, l);
      f16x8 w1 = load_bq<USE_WS>(ws, Wqkv, kc, 24 + cv0 + 1, l);
      f16x8 w2 = load_bq<USE_WS>(ws, Wqkv, kc, 24 + cv0 + 2, l);
#pragma unroll
      for (int t = 0; t < 4; ++t) {
        av[0][t] = MFMA16(xf[t], w0, av[0][t]);
        av[1][t] = MFMA16(xf[t], w1, av[1][t]);
        av[2][t] = MFMA16(xf[t], w2, av[2][t]);
      }
    }

#pragma unroll
    for (int ci = 0; ci < 3; ++ci) {
      int vch = (cv0 + ci) * 16 + l15;            // 0..191
      float bv_ = bqkv[384 + vch];
#pragma unroll
      for (int t = 0; t < 4; ++t) {
        f16x4 v = pk4(av[ci][t][0] + bv_, av[ci][t][1] + bv_,
                      av[ci][t][2] + bv_, av[ci][t][3] + bv_);
        *(f16x4*)&s_vT[(vch * 9 + 2 * t + (lg >> 1)) * 8 + (lg & 1) * 4] = v;
      }
    }
  }
  __syncthreads();

  // ---------------- Phase 2: attention (S^T / O^T), log2-domain softmax -----
  {
    const int pt = wv & 3, hi = wv >> 2;
    const int h_first = (hi < 2) ? (hi * 2) : (hi + 2);   // heads 0,2,4,5 base
    const int h_count = (hi < 2) ? 2 : 1;
    const int p = 16 * pt + l15;
    const int pi = p / 7, pj = p - pi * 7;
    int moff[16];
    unsigned mbits = 0;
#pragma unroll
    for (int jq = 0; jq < 4; ++jq)
#pragma unroll
      for (int r = 0; r < 4; ++r) {
        int q = 16 * jq + lg * 4 + r;
        int qi = q / 7, qj = q - qi * 7;
        bool bad = (q >= 49) || (p >= 49) ||
                   ((wi == 63) && ((pi < 4) != (qi < 4))) ||
                   ((wj == 63) && ((pj < 4) != (qj < 4)));
        int idx = jq * 4 + r;
        moff[idx] = bad ? 0 : (pi - qi + 6) * 13 + (pj - qj + 6);
        if (bad) mbits |= (1u << idx);
      }

    for (int e = 0; e < h_count; ++e) {
      int h = h_first + e;
      // S^T = K · Q^T : lane holds col p, rows q = 16jq + lg*4 + r
      f16x8 aq = *(const f16x8*)&s_qk[(p * 25 + h * 4 + lg) * 8];
      f32x4 sc[4];
      __builtin_amdgcn_s_setprio(1);
#pragma unroll
      for (int jq = 0; jq < 4; ++jq) {
        f16x8 bk = *(const f16x8*)&s_qk[(1600 + (16 * jq + l15) * 25 + h * 4 + lg) * 8];
        sc[jq] = MFMA16(bk, aq, zero4);
      }
      __builtin_amdgcn_s_setprio(0);
      float sv[16];
      float mx = -3.0e38f;
#pragma unroll
      for (int jq = 0; jq < 4; ++jq)
#pragma unroll
        for (int r = 0; r < 4; ++r) {
          int idx = jq * 4 + r;
          float s = (mbits >> idx & 1u) ? -1.0e30f
                                        : sc[jq][r] + s_add[h * 169 + moff[idx]];
          sv[idx] = s;
          mx = fmaxf(mx, s);
        }
      mx = fmaxf(mx, __shfl_xor(mx, 16));
      mx = fmaxf(mx, __shfl_xor(mx, 32));
      float sum = 0.0f;
#pragma unroll
      for (int i = 0; i < 16; ++i) {
        float ev = exp2f(sv[i] - mx);
        sv[i] = ev;
        sum += ev;
      }
      // store UNNORMALIZED P immediately (decoupled from sum reduction)
#pragma unroll
      for (int jq = 0; jq < 4; ++jq) {
        f16x4 v = pk4(sv[jq * 4], sv[jq * 4 + 1], sv[jq * 4 + 2], sv[jq * 4 + 3]);
        *(f16x4*)&s_p[(hi * 576 + p * 9 + 2 * jq + (lg >> 1)) * 8 + (lg & 1) * 4] = v;
      }
      sum += __shfl_xor(sum, 16);
      sum += __shfl_xor(sum, 32);
      float inv = 1.0f / sum;
      // O^T = V^T · P^T : lane holds col p, rows = channels; scale by inv after
      f32x4 o[2] = {zero4, zero4};
      __builtin_amdgcn_s_setprio(1);
#pragma unroll
      for (int kq = 0; kq < 2; ++kq) {
        f16x8 ap = *(const f16x8*)&s_p[(hi * 576 + p * 9 + kq * 4 + lg) * 8];
#pragma unroll
        for (int jn = 0; jn < 2; ++jn) {
          int ch = h * 32 + jn * 16 + l15;
          f16x8 bvv = *(const f16x8*)&s_vT[(ch * 9 + kq * 4 + lg) * 8];
          o[jn] = MFMA16(bvv, ap, o[jn]);
        }
      }
      __builtin_amdgcn_s_setprio(0);
#pragma unroll
      for (int jn = 0; jn < 2; ++jn) {
        int ch0 = h * 32 + jn * 16 + lg * 4;
        f16x4 v = pk4(o[jn][0] * inv, o[jn][1] * inv, o[jn][2] * inv, o[jn][3] * inv);
        *(f16x4*)&s_x[(p * 25 + (ch0 >> 3)) * 8 + (ch0 & 7)] = v;
      }
    }
  }
  __syncthreads();

  // ---------------- Phase 3: out-proj + scatter (addr once per row) ---------
  {
    const int tt = wv >> 2, cg = wv & 3;   // token-tile, ch-group (3 tiles)
    f32x4 acc3[3];
#pragma unroll
    for (int j = 0; j < 3; ++j) acc3[j] = zero4;

#pragma unroll
    for (int kc = 0; kc < 6; ++kc) {
      f16x8 a = *(const f16x8*)&s_x[((tt * 16 + l15) * 25 + kc * 4 + lg) * 8];
      f16x8 b0 = load_bo<USE_WS>(ws, Wout, kc, 3 * cg, l);
      f16x8 b1 = load_bo<USE_WS>(ws, Wout, kc, 3 * cg + 1, l);
      f16x8 b2 = load_bo<USE_WS>(ws, Wout, kc, 3 * cg + 2, l);
      acc3[0] = MFMA16(a, b0, acc3[0]);
      acc3[1] = MFMA16(a, b1, acc3[1]);
      acc3[2] = MFMA16(a, b2, acc3[2]);
    }

    const int rr = wi >> 4, w1i = wi & 15;
    const float bias0 = bout[cg * 48 + l15];
    const float bias1 = bout[cg * 48 + 16 + l15];
    const float bias2 = bout[cg * 48 + 32 + l15];
#pragma unroll
    for (int r = 0; r < 4; ++r) {
      int pp = tt * 16 + lg * 4 + r;
      if (pp < 49) {
        int i2 = pp / 7, j2 = pp - i2 * 7;
        int y = w1i * 7 + i2 + 3;  if (y >= 112) y -= 112;
        int xc = wj * 7 + j2 + 3;  if (xc >= 448) xc -= 448;
        float* base = out + (size_t)(y * 448 + xc) * 768 + rr * 192 + cg * 48 + l15;
        __builtin_nontemporal_store(acc3[0][r] + bias0, base);
        __builtin_nontemporal_store(acc3[1][r] + bias1, base + 16);
        __builtin_nontemporal_store(acc3[2][r] + bias2, base + 32);
      }
    }
  }
}

extern "C" void kernel_launch(void* const* d_in, const int* in_sizes, int n_in,
                              void* d_out, int out_size, void* d_ws, size_t ws_size,
                              hipStream_t stream) {
  const float* x      = (const float*)d_in[0];
  const float* Wqkv   = (const float*)d_in[1];
  const float* bqkv   = (const float*)d_in[2];
  const float* relpos = (const float*)d_in[3];
  const float* Wout   = (const float*)d_in[4];
  const float* bout   = (const float*)d_in[5];
  float* out = (float*)d_out;
  f16* ws = (f16*)d_ws;

  if (ws_size >= (size_t)(110592 + 36864) * sizeof(f16)) {
    wmsa_prep<<<72, 256, 0, stream>>>(Wqkv, Wout, ws);
    wmsa_main<true><<<4096, 1024, 0, stream>>>(x, Wqkv, bqkv, relpos, Wout, bout, ws, out);
  } else {
    wmsa_main<false><<<4096, 1024, 0, stream>>>(x, Wqkv, bqkv, relpos, Wout, bout, ws, out);
  }
}

// Round 9
// 187.391 us; speedup vs baseline: 5.6005x; 1.0649x over previous
//
#include <hip/hip_runtime.h>

typedef _Float16 f16;
typedef _Float16 f16x8 __attribute__((ext_vector_type(8)));
typedef _Float16 f16x4 __attribute__((ext_vector_type(4)));
typedef _Float16 f16x2 __attribute__((ext_vector_type(2)));
typedef float f32x4 __attribute__((ext_vector_type(4)));

#define MFMA16(a, b, c) __builtin_amdgcn_mfma_f32_16x16x32_f16(a, b, c, 0, 0, 0)

// ws layout (f16 elements): [0, 110592)   W_qkv frags
//                           [110592, 147456) W_out frags
//                           byte 294912: f32 bias table [6][64][68]  (104448 B)
#define WS_BIAS_ELEM 147456
#define WS_NEED (294912 + 104448)

__device__ __forceinline__ f16x2 pkcvt(float a, float b) {
  auto r = __builtin_amdgcn_cvt_pkrtz(a, b);   // __fp16 ext_vector(2)
  union { decltype(r) i; f16x2 o; } u;
  u.i = r;
  return u.o;
}

__device__ __forceinline__ f16x4 pk4(float a, float b, float c, float d) {
  union { f16x2 h2[2]; f16x4 h4; } u;
  u.h2[0] = pkcvt(a, b);
  u.h2[1] = pkcvt(c, d);
  return u.h4;
}

// RTZ packed convert of 8 consecutive f32 (main kernel hot path)
__device__ __forceinline__ f16x8 cvt8z(const float* p) {
  const float4* s = (const float4*)p;
  float4 u0 = s[0], u1 = s[1];
  union { f16x2 h2[4]; f16x8 h8; } u;
  u.h2[0] = pkcvt(u0.x, u0.y);
  u.h2[1] = pkcvt(u0.z, u0.w);
  u.h2[2] = pkcvt(u1.x, u1.y);
  u.h2[3] = pkcvt(u1.z, u1.w);
  return u.h8;
}

// RTE convert (prep kernel / fallback path — accuracy-first)
__device__ __forceinline__ f16x8 cvt8(const float* p) {
  const float4* s = (const float4*)p;
  float4 u0 = s[0], u1 = s[1];
  f16x8 v;
  v[0] = (f16)u0.x; v[1] = (f16)u0.y; v[2] = (f16)u0.z; v[3] = (f16)u0.w;
  v[4] = (f16)u1.x; v[5] = (f16)u1.y; v[6] = (f16)u1.z; v[7] = (f16)u1.w;
  return v;
}

// ---- prep: W frags (f16) + bias table (f32) ----
__global__ void wmsa_prep(const float* __restrict__ Wqkv,
                          const float* __restrict__ Wout,
                          const float* __restrict__ relpos,
                          f16* __restrict__ ws) {
  int gid = blockIdx.x * 256 + threadIdx.x;
  if (gid < 13824) {
    int fb = gid >> 6, l = gid & 63;
    int kc = fb / 36, nt = fb - kc * 36;
    int n = nt * 16 + (l & 15), k = kc * 32 + (l >> 4) * 8;
    *(f16x8*)(ws + (size_t)gid * 8) = cvt8(Wqkv + (size_t)n * 192 + k);
  } else if (gid < 18432) {
    int g2 = gid - 13824;
    int fb = g2 >> 6, l = g2 & 63;
    int kc = fb / 12, nt = fb - kc * 12;
    int n = nt * 16 + (l & 15), k = kc * 32 + (l >> 4) * 8;
    *(f16x8*)(ws + 110592 + (size_t)g2 * 8) = cvt8(Wout + (size_t)n * 192 + k);
  } else if (gid < 18432 + 26112) {
    int g3 = gid - 18432;                  // [6][64 p][68 q]
    int h = g3 / 4352, rem = g3 - h * 4352;
    int p = rem / 68, q = rem - p * 68;
    float v = 0.0f;
    if (q >= 49) v = -30000.0f;
    else if (p < 49) {
      int pi = p / 7, pj = p - pi * 7;
      int qi = q / 7, qj = q - qi * 7;
      int di = pi - qi, dj = pj - qj;
      float g = __expf((float)(di * di + dj * dj) * (-9.0f / 98.0f));
      v = (relpos[h * 169 + (di + 6) * 13 + (dj + 6)] + g) * 1.4426950408889634f;
    }
    ((float*)(ws + WS_BIAS_ELEM))[g3] = v;
  }
}

template <bool USE_WS>
__device__ __forceinline__ f16x8 load_bq(const f16* wsq, const float* Wqkv,
                                         int kc, int nt, int l) {
  if constexpr (USE_WS) {
    return *(const f16x8*)(wsq + (size_t)(kc * 36 + nt) * 512 + l * 8);
  } else {
    int n = nt * 16 + (l & 15), k = kc * 32 + (l >> 4) * 8;
    return cvt8(Wqkv + (size_t)n * 192 + k);
  }
}

template <bool USE_WS>
__device__ __forceinline__ f16x8 load_bo(const f16* wsq, const float* Wout,
                                         int kc, int nt, int l) {
  if constexpr (USE_WS) {
    return *(const f16x8*)(wsq + 110592 + (size_t)(kc * 12 + nt) * 512 + l * 8);
  } else {
    int n = nt * 16 + (l & 15), k = kc * 32 + (l >> 4) * 8;
    return cvt8(Wout + (size_t)n * 192 + k);
  }
}

// One block per 7x7 window, 1024 threads = 16 waves = 4 waves/SIMD.
template <bool USE_WS>
__global__ __launch_bounds__(1024, 1) void wmsa_main(
    const float* __restrict__ x,
    const float* __restrict__ Wqkv,
    const float* __restrict__ bqkv,
    const float* __restrict__ relpos,
    const float* __restrict__ Wout,
    const float* __restrict__ bout,
    const f16* __restrict__ ws,
    float* __restrict__ out)
{
  __shared__ __align__(16) f16 s_x[1600 * 8];   // [64 tok][25g]           25600 B
  __shared__ __align__(16) f16 s_qk[3200 * 8];  // q,k: 2 x [64 tok][25g]  51200 B
  __shared__ __align__(16) f16 s_vT[1728 * 8];  // v^T [192 ch][9g]        27648 B
  __shared__ __align__(16) f16 s_p[2304 * 8];   // P [4 hi][64 p][9g]      36864 B
  __shared__ float s_add[1014];                 // fallback bias table      4056 B
  __shared__ int s_addr[64];                    // scatter LUT               256 B

  const int tid = threadIdx.x;
  const int wi = blockIdx.x >> 6, wj = blockIdx.x & 63;
  const int wv = tid >> 6;
  const int l = tid & 63;
  const int l15 = l & 15, lg = l >> 4;
  const f32x4 zero4 = {0.f, 0.f, 0.f, 0.f};
  const float QMULT = 0.17677669529663687f * 1.4426950408889634f; // scale*log2e

  // ---------------- Phase 0: LUTs + rolled x window (f16) -------------------
  if constexpr (!USE_WS) {
    for (int i = tid; i < 1014; i += 1024) {
      int rem = i % 169;
      int di = rem / 13 - 6, dj = rem % 13 - 6;
      s_add[i] = (relpos[i] + __expf((float)(di * di + dj * dj) * (-9.0f / 98.0f)))
                 * 1.4426950408889634f;
    }
  }
  if (tid < 64) {
    int val = 0;
    if (tid < 49) {
      int i2 = tid / 7, j2 = tid - i2 * 7;
      int y = (wi & 15) * 7 + i2 + 3;  if (y >= 112) y -= 112;
      int xc = wj * 7 + j2 + 3;        if (xc >= 448) xc -= 448;
      val = (y * 448 + xc) * 768;
    }
    s_addr[tid] = val;
  }
  for (int gid = tid; gid < 1536; gid += 1024) {
    int t = gid / 24, g = gid - t * 24;
    f16x8 v;
    if (t < 49) {
      int hh = wi * 7 + t / 7 + 3; if (hh >= 448) hh -= 448;
      int ww = wj * 7 + t % 7 + 3; if (ww >= 448) ww -= 448;
      v = cvt8z(x + (size_t)(hh * 448 + ww) * 192 + g * 8);
    } else {
#pragma unroll
      for (int e = 0; e < 8; ++e) v[e] = (f16)0.0f;
    }
    *(f16x8*)&s_x[(t * 25 + g) * 8] = v;
  }
  __syncthreads();

  // ---------------- Phase 1: QKV. waves 0-11: q/k (swapped); 12-15: v -------
  if (wv < 12) {
    f32x4 aqk[2][4];
#pragma unroll
    for (int ci = 0; ci < 2; ++ci)
#pragma unroll
      for (int t = 0; t < 4; ++t) aqk[ci][t] = zero4;

#pragma unroll
    for (int kc = 0; kc < 6; ++kc) {
      f16x8 xf[4];
#pragma unroll
      for (int t = 0; t < 4; ++t)
        xf[t] = *(const f16x8*)&s_x[((t * 16 + l15) * 25 + kc * 4 + lg) * 8];
      f16x8 wq0 = load_bq<USE_WS>(ws, Wqkv, kc, 2 * wv, l);
      f16x8 wq1 = load_bq<USE_WS>(ws, Wqkv, kc, 2 * wv + 1, l);
#pragma unroll
      for (int t = 0; t < 4; ++t) aqk[0][t] = MFMA16(wq0, xf[t], aqk[0][t]);
#pragma unroll
      for (int t = 0; t < 4; ++t) aqk[1][t] = MFMA16(wq1, xf[t], aqk[1][t]);
    }

#pragma unroll
    for (int ci = 0; ci < 2; ++ci) {
      int c0 = (2 * wv + ci) * 16 + lg * 4;       // 0..383
      float4 b4 = *(const float4*)(bqkv + c0);
      int part = (c0 >= 192) ? 1 : 0;
      int ch = c0 - part * 192;
      float mult = part ? 1.0f : QMULT;
      float bx = b4.x * mult, by = b4.y * mult, bz = b4.z * mult, bw = b4.w * mult;
      int gbase = part * 1600 + (ch >> 3);
      int sub = ch & 7;
#pragma unroll
      for (int t = 0; t < 4; ++t) {
        int tok = t * 16 + l15;
        f16x4 v = pk4(fmaf(aqk[ci][t][0], mult, bx), fmaf(aqk[ci][t][1], mult, by),
                      fmaf(aqk[ci][t][2], mult, bz), fmaf(aqk[ci][t][3], mult, bw));
        *(f16x4*)&s_qk[(gbase + tok * 25) * 8 + sub] = v;
      }
    }
  } else {
    const int cv0 = (wv - 12) * 3;
    f32x4 av[3][4];
#pragma unroll
    for (int ci = 0; ci < 3; ++ci)
#pragma unroll
      for (int t = 0; t < 4; ++t) av[ci][t] = zero4;

#pragma unroll
    for (int kc = 0; kc < 6; ++kc) {
      f16x8 xf[4];
#pragma unroll
      for (int t = 0; t < 4; ++t)
        xf[t] = *(const f16x8*)&s_x[((t * 16 + l15) * 25 + kc * 4 + lg) * 8];
      f16x8 w0 = load_bq<USE_WS>(ws, Wqkv, kc, 24 + cv0, l);
      f16x8 w1 = load_bq<USE_WS>(ws, Wqkv, kc, 24 + cv0 + 1, l);
      f16x8 w2 = load_bq<USE_WS>(ws, Wqkv, kc, 24 + cv0 + 2, l);
#pragma unroll
      for (int t = 0; t < 4; ++t) {
        av[0][t] = MFMA16(xf[t], w0, av[0][t]);
        av[1][t] = MFMA16(xf[t], w1, av[1][t]);
        av[2][t] = MFMA16(xf[t], w2, av[2][t]);
      }
    }

#pragma unroll
    for (int ci = 0; ci < 3; ++ci) {
      int vch = (cv0 + ci) * 16 + l15;            // 0..191
      float bv_ = bqkv[384 + vch];
#pragma unroll
      for (int t = 0; t < 4; ++t) {
        f16x4 v = pk4(av[ci][t][0] + bv_, av[ci][t][1] + bv_,
                      av[ci][t][2] + bv_, av[ci][t][3] + bv_);
        *(f16x4*)&s_vT[(vch * 9 + 2 * t + (lg >> 1)) * 8 + (lg & 1) * 4] = v;
      }
    }
  }
  __syncthreads();

  // ---------------- Phase 2: attention (S^T / O^T), log2-domain softmax -----
  {
    const int pt = wv & 3, hi = wv >> 2;
    const int h_first = (hi < 2) ? (hi * 2) : (hi + 2);   // heads 0,2,4,5 base
    const int h_count = (hi < 2) ? 2 : 1;
    const int p = 16 * pt + l15;
    const bool edge = (wi == 63) || (wj == 63);

    // fallback path keeps the old moff gather; fast path needs mbits only on edges
    int moff[16];
    unsigned mbits = 0;
    if (edge || !USE_WS) {
      int pi = p / 7, pj = p - pi * 7;
#pragma unroll
      for (int jq = 0; jq < 4; ++jq)
#pragma unroll
        for (int r = 0; r < 4; ++r) {
          int q = 16 * jq + lg * 4 + r;
          int qi = q / 7, qj = q - qi * 7;
          bool bad = (q >= 49) || (p >= 49) ||
                     ((wi == 63) && ((pi < 4) != (qi < 4))) ||
                     ((wj == 63) && ((pj < 4) != (qj < 4)));
          int idx = jq * 4 + r;
          moff[idx] = bad ? 0 : (pi - qi + 6) * 13 + (pj - qj + 6);
          if (bad) mbits |= (1u << idx);
        }
    }
    const float* bias_base = (const float*)(ws + WS_BIAS_ELEM) + p * 68 + lg * 4;

    for (int e = 0; e < h_count; ++e) {
      int h = h_first + e;
      // S^T = K · Q^T : lane holds col p, rows q = 16jq + lg*4 + r
      f16x8 aq = *(const f16x8*)&s_qk[(p * 25 + h * 4 + lg) * 8];
      f32x4 sc[4];
      __builtin_amdgcn_s_setprio(1);
#pragma unroll
      for (int jq = 0; jq < 4; ++jq) {
        f16x8 bk = *(const f16x8*)&s_qk[(1600 + (16 * jq + l15) * 25 + h * 4 + lg) * 8];
        sc[jq] = MFMA16(bk, aq, zero4);
      }
      __builtin_amdgcn_s_setprio(0);
      float sv[16];
      float mx = -3.0e38f;
      if constexpr (USE_WS) {
        f32x4 bb[4];
#pragma unroll
        for (int jq = 0; jq < 4; ++jq)
          bb[jq] = *(const f32x4*)(bias_base + h * 4352 + 16 * jq);
        if (!edge) {
#pragma unroll
          for (int jq = 0; jq < 4; ++jq)
#pragma unroll
            for (int r = 0; r < 4; ++r) {
              float s = sc[jq][r] + bb[jq][r];
              sv[jq * 4 + r] = s;
              mx = fmaxf(mx, s);
            }
        } else {
#pragma unroll
          for (int jq = 0; jq < 4; ++jq)
#pragma unroll
            for (int r = 0; r < 4; ++r) {
              int idx = jq * 4 + r;
              float s = (mbits >> idx & 1u) ? -30000.0f : sc[jq][r] + bb[jq][r];
              sv[idx] = s;
              mx = fmaxf(mx, s);
            }
        }
      } else {
#pragma unroll
        for (int jq = 0; jq < 4; ++jq)
#pragma unroll
          for (int r = 0; r < 4; ++r) {
            int idx = jq * 4 + r;
            float s = (mbits >> idx & 1u) ? -30000.0f
                                          : sc[jq][r] + s_add[h * 169 + moff[idx]];
            sv[idx] = s;
            mx = fmaxf(mx, s);
          }
      }
      mx = fmaxf(mx, __shfl_xor(mx, 16));
      mx = fmaxf(mx, __shfl_xor(mx, 32));
      float sum = 0.0f;
#pragma unroll
      for (int i = 0; i < 16; ++i) {
        float ev = exp2f(sv[i] - mx);
        sv[i] = ev;
        sum += ev;
      }
      // store UNNORMALIZED P immediately (decoupled from sum reduction)
#pragma unroll
      for (int jq = 0; jq < 4; ++jq) {
        f16x4 v = pk4(sv[jq * 4], sv[jq * 4 + 1], sv[jq * 4 + 2], sv[jq * 4 + 3]);
        *(f16x4*)&s_p[(hi * 576 + p * 9 + 2 * jq + (lg >> 1)) * 8 + (lg & 1) * 4] = v;
      }
      sum += __shfl_xor(sum, 16);
      sum += __shfl_xor(sum, 32);
      float inv = 1.0f / sum;
      // O^T = V^T · P^T : lane holds col p, rows = channels; scale by inv after
      f32x4 o[2] = {zero4, zero4};
      __builtin_amdgcn_s_setprio(1);
#pragma unroll
      for (int kq = 0; kq < 2; ++kq) {
        f16x8 ap = *(const f16x8*)&s_p[(hi * 576 + p * 9 + kq * 4 + lg) * 8];
#pragma unroll
        for (int jn = 0; jn < 2; ++jn) {
          int ch = h * 32 + jn * 16 + l15;
          f16x8 bvv = *(const f16x8*)&s_vT[(ch * 9 + kq * 4 + lg) * 8];
          o[jn] = MFMA16(bvv, ap, o[jn]);
        }
      }
      __builtin_amdgcn_s_setprio(0);
#pragma unroll
      for (int jn = 0; jn < 2; ++jn) {
        int ch0 = h * 32 + jn * 16 + lg * 4;
        f16x4 v = pk4(o[jn][0] * inv, o[jn][1] * inv, o[jn][2] * inv, o[jn][3] * inv);
        *(f16x4*)&s_x[(p * 25 + (ch0 >> 3)) * 8 + (ch0 & 7)] = v;
      }
    }
  }
  __syncthreads();

  // ---------------- Phase 3: out-proj + LUT scatter -------------------------
  {
    const int tt = wv >> 2, cg = wv & 3;   // token-tile, ch-group (3 tiles)
    f32x4 acc3[3];
#pragma unroll
    for (int j = 0; j < 3; ++j) acc3[j] = zero4;

#pragma unroll
    for (int kc = 0; kc < 6; ++kc) {
      f16x8 a = *(const f16x8*)&s_x[((tt * 16 + l15) * 25 + kc * 4 + lg) * 8];
      f16x8 b0 = load_bo<USE_WS>(ws, Wout, kc, 3 * cg, l);
      f16x8 b1 = load_bo<USE_WS>(ws, Wout, kc, 3 * cg + 1, l);
      f16x8 b2 = load_bo<USE_WS>(ws, Wout, kc, 3 * cg + 2, l);
      acc3[0] = MFMA16(a, b0, acc3[0]);
      acc3[1] = MFMA16(a, b1, acc3[1]);
      acc3[2] = MFMA16(a, b2, acc3[2]);
    }

    const int rr = wi >> 4;
    const int lane_off = rr * 192 + cg * 48 + l15;
    const float bias0 = bout[cg * 48 + l15];
    const float bias1 = bout[cg * 48 + 16 + l15];
    const float bias2 = bout[cg * 48 + 32 + l15];
#pragma unroll
    for (int r = 0; r < 4; ++r) {
      int pp = tt * 16 + lg * 4 + r;
      if (pp < 49) {
        float* base = out + s_addr[pp] + lane_off;
        __builtin_nontemporal_store(acc3[0][r] + bias0, base);
        __builtin_nontemporal_store(acc3[1][r] + bias1, base + 16);
        __builtin_nontemporal_store(acc3[2][r] + bias2, base + 32);
      }
    }
  }
}

extern "C" void kernel_launch(void* const* d_in, const int* in_sizes, int n_in,
                              void* d_out, int out_size, void* d_ws, size_t ws_size,
                              hipStream_t stream) {
  const float* x      = (const float*)d_in[0];
  const float* Wqkv   = (const float*)d_in[1];
  const float* bqkv   = (const float*)d_in[2];
  const float* relpos = (const float*)d_in[3];
  const float* Wout   = (const float*)d_in[4];
  const float* bout   = (const float*)d_in[5];
  float* out = (float*)d_out;
  f16* ws = (f16*)d_ws;

  if (ws_size >= (size_t)WS_NEED) {
    wmsa_prep<<<174, 256, 0, stream>>>(Wqkv, Wout, relpos, ws);
    wmsa_main<true><<<4096, 1024, 0, stream>>>(x, Wqkv, bqkv, relpos, Wout, bout, ws, out);
  } else {
    wmsa_main<false><<<4096, 1024, 0, stream>>>(x, Wqkv, bqkv, relpos, Wout, bout, ws, out);
  }
}

// Round 10
// 187.122 us; speedup vs baseline: 5.6086x; 1.0014x over previous
//
#include <hip/hip_runtime.h>

typedef _Float16 f16;
typedef _Float16 f16x8 __attribute__((ext_vector_type(8)));
typedef _Float16 f16x4 __attribute__((ext_vector_type(4)));
typedef _Float16 f16x2 __attribute__((ext_vector_type(2)));
typedef float f32x4 __attribute__((ext_vector_type(4)));

#define MFMA16(a, b, c) __builtin_amdgcn_mfma_f32_16x16x32_f16(a, b, c, 0, 0, 0)

// ws layout (f16 elems): [0,110592) Wqkv frags | [110592,147456) Wout frags
//                        byte 294912: f32 bias table [6][64][68] (104448 B)
#define WS_BIAS_ELEM 147456
#define WS_NEED (294912 + 104448)

// LDS arena granule (16 B) offsets — total 10000 granules = 160000 B
#define G_Q    0      // q  [64 tok][25g]
#define G_K    1600   // k  [64 tok][25g]
#define G_VT   3200   // v^T [192 ch][9g]
#define G_O    4928   // attn out [64 tok][25g]
#define G_P    6528   // P: 6 regions x 576g (aliases x-input staging)
#define G_XIN  6528   // x window [64 tok][25g] (dead after phase 1)
#define G_ADDR 9984   // int[64] scatter LUT

__device__ __forceinline__ f16x2 pkcvt(float a, float b) {
  auto r = __builtin_amdgcn_cvt_pkrtz(a, b);
  union { decltype(r) i; f16x2 o; } u;
  u.i = r;
  return u.o;
}

__device__ __forceinline__ f16x4 pk4(float a, float b, float c, float d) {
  union { f16x2 h2[2]; f16x4 h4; } u;
  u.h2[0] = pkcvt(a, b);
  u.h2[1] = pkcvt(c, d);
  return u.h4;
}

__device__ __forceinline__ f16x8 cvt8z(const float* p) {
  const float4* s = (const float4*)p;
  float4 u0 = s[0], u1 = s[1];
  union { f16x2 h2[4]; f16x8 h8; } u;
  u.h2[0] = pkcvt(u0.x, u0.y);
  u.h2[1] = pkcvt(u0.z, u0.w);
  u.h2[2] = pkcvt(u1.x, u1.y);
  u.h2[3] = pkcvt(u1.z, u1.w);
  return u.h8;
}

__device__ __forceinline__ f16x8 cvt8(const float* p) {
  const float4* s = (const float4*)p;
  float4 u0 = s[0], u1 = s[1];
  f16x8 v;
  v[0] = (f16)u0.x; v[1] = (f16)u0.y; v[2] = (f16)u0.z; v[3] = (f16)u0.w;
  v[4] = (f16)u1.x; v[5] = (f16)u1.y; v[6] = (f16)u1.z; v[7] = (f16)u1.w;
  return v;
}

// ---- prep: W frags (f16, RTE) + bias table (f32) ----
__global__ void wmsa_prep(const float* __restrict__ Wqkv,
                          const float* __restrict__ Wout,
                          const float* __restrict__ relpos,
                          f16* __restrict__ ws) {
  int gid = blockIdx.x * 256 + threadIdx.x;
  if (gid < 13824) {
    int fb = gid >> 6, l = gid & 63;
    int kc = fb / 36, nt = fb - kc * 36;
    int n = nt * 16 + (l & 15), k = kc * 32 + (l >> 4) * 8;
    *(f16x8*)(ws + (size_t)gid * 8) = cvt8(Wqkv + (size_t)n * 192 + k);
  } else if (gid < 18432) {
    int g2 = gid - 13824;
    int fb = g2 >> 6, l = g2 & 63;
    int kc = fb / 12, nt = fb - kc * 12;
    int n = nt * 16 + (l & 15), k = kc * 32 + (l >> 4) * 8;
    *(f16x8*)(ws + 110592 + (size_t)g2 * 8) = cvt8(Wout + (size_t)n * 192 + k);
  } else if (gid < 18432 + 26112) {
    int g3 = gid - 18432;                  // [6][64 p][68 q]
    int h = g3 / 4352, rem = g3 - h * 4352;
    int p = rem / 68, q = rem - p * 68;
    float v = 0.0f;
    if (q >= 49) v = -30000.0f;
    else if (p < 49) {
      int pi = p / 7, pj = p - pi * 7;
      int qi = q / 7, qj = q - qi * 7;
      int di = pi - qi, dj = pj - qj;
      float g = __expf((float)(di * di + dj * dj) * (-9.0f / 98.0f));
      v = (relpos[h * 169 + (di + 6) * 13 + (dj + 6)] + g) * 1.4426950408889634f;
    }
    ((float*)(ws + WS_BIAS_ELEM))[g3] = v;
  }
}

template <bool USE_WS>
__device__ __forceinline__ f16x8 load_bq(const f16* wsq, const float* Wqkv,
                                         int kc, int nt, int l) {
  if constexpr (USE_WS) {
    return *(const f16x8*)(wsq + (size_t)(kc * 36 + nt) * 512 + l * 8);
  } else {
    int n = nt * 16 + (l & 15), k = kc * 32 + (l >> 4) * 8;
    return cvt8(Wqkv + (size_t)n * 192 + k);
  }
}

template <bool USE_WS>
__device__ __forceinline__ f16x8 load_bo(const f16* wsq, const float* Wout,
                                         int kc, int nt, int l) {
  if constexpr (USE_WS) {
    return *(const f16x8*)(wsq + 110592 + (size_t)(kc * 12 + nt) * 512 + l * 8);
  } else {
    int n = nt * 16 + (l & 15), k = kc * 32 + (l >> 4) * 8;
    return cvt8(Wout + (size_t)n * 192 + k);
  }
}

// NH heads processed with interleaved (independent) chains. No-max softmax.
template <int NH>
__device__ __forceinline__ void attn_fast(
    f16* smem, const float* bb_base, int h0,
    int p, int lg, int l15, unsigned mbits, bool edge)
{
  const f32x4 zero4 = {0.f, 0.f, 0.f, 0.f};
  f16x8 aq[NH];
  f32x4 sc[NH][4];
#pragma unroll
  for (int e = 0; e < NH; ++e)
    aq[e] = *(const f16x8*)&smem[(G_Q + p * 25 + (h0 + e) * 4 + lg) * 8];
  __builtin_amdgcn_s_setprio(1);
#pragma unroll
  for (int e = 0; e < NH; ++e)
#pragma unroll
    for (int jq = 0; jq < 4; ++jq) {
      f16x8 bk = *(const f16x8*)&smem[(G_K + (16 * jq + l15) * 25 + (h0 + e) * 4 + lg) * 8];
      sc[e][jq] = MFMA16(bk, aq[e], zero4);
    }
  __builtin_amdgcn_s_setprio(0);

  float sv[NH][16];
  float sum[NH];
#pragma unroll
  for (int e = 0; e < NH; ++e) {
    sum[e] = 0.0f;
    if (!edge) {
#pragma unroll
      for (int jq = 0; jq < 4; ++jq) {
        f32x4 bb = *(const f32x4*)(bb_base + (h0 + e) * 4352 + 16 * jq);
#pragma unroll
        for (int r = 0; r < 4; ++r) {
          float ev = exp2f(sc[e][jq][r] + bb[r]);
          sv[e][jq * 4 + r] = ev;
          sum[e] += ev;
        }
      }
    } else {
#pragma unroll
      for (int jq = 0; jq < 4; ++jq) {
        f32x4 bb = *(const f32x4*)(bb_base + (h0 + e) * 4352 + 16 * jq);
#pragma unroll
        for (int r = 0; r < 4; ++r) {
          int idx = jq * 4 + r;
          float s = (mbits >> idx & 1u) ? -30000.0f : sc[e][jq][r] + bb[r];
          float ev = exp2f(s);
          sv[e][idx] = ev;
          sum[e] += ev;
        }
      }
    }
  }
  // store UNNORMALIZED P (per-head region: no cross-head hazard)
#pragma unroll
  for (int e = 0; e < NH; ++e)
#pragma unroll
    for (int jq = 0; jq < 4; ++jq) {
      f16x4 v = pk4(sv[e][jq * 4], sv[e][jq * 4 + 1], sv[e][jq * 4 + 2], sv[e][jq * 4 + 3]);
      *(f16x4*)&smem[(G_P + (h0 + e) * 576 + p * 9 + 2 * jq + (lg >> 1)) * 8 + (lg & 1) * 4] = v;
    }
  float inv[NH];
#pragma unroll
  for (int e = 0; e < NH; ++e) {
    float s2 = sum[e] + __shfl_xor(sum[e], 16);
    s2 += __shfl_xor(s2, 32);
    inv[e] = __builtin_amdgcn_rcpf(s2);
  }
  f32x4 o[NH][2];
#pragma unroll
  for (int e = 0; e < NH; ++e) { o[e][0] = zero4; o[e][1] = zero4; }
  __builtin_amdgcn_s_setprio(1);
#pragma unroll
  for (int e = 0; e < NH; ++e)
#pragma unroll
    for (int kq = 0; kq < 2; ++kq) {
      f16x8 ap = *(const f16x8*)&smem[(G_P + (h0 + e) * 576 + p * 9 + kq * 4 + lg) * 8];
#pragma unroll
      for (int jn = 0; jn < 2; ++jn) {
        int ch = (h0 + e) * 32 + jn * 16 + l15;
        f16x8 bv = *(const f16x8*)&smem[(G_VT + ch * 9 + kq * 4 + lg) * 8];
        o[e][jn] = MFMA16(bv, ap, o[e][jn]);
      }
    }
  __builtin_amdgcn_s_setprio(0);
#pragma unroll
  for (int e = 0; e < NH; ++e)
#pragma unroll
    for (int jn = 0; jn < 2; ++jn) {
      int ch0 = (h0 + e) * 32 + jn * 16 + lg * 4;
      f16x4 v = pk4(o[e][jn][0] * inv[e], o[e][jn][1] * inv[e],
                    o[e][jn][2] * inv[e], o[e][jn][3] * inv[e]);
      *(f16x4*)&smem[(G_O + p * 25 + (ch0 >> 3)) * 8 + (ch0 & 7)] = v;
    }
}

// One block per 7x7 window, 1024 threads = 16 waves = 4 waves/SIMD.
template <bool USE_WS>
__global__ __launch_bounds__(1024, 1) void wmsa_main(
    const float* __restrict__ x,
    const float* __restrict__ Wqkv,
    const float* __restrict__ bqkv,
    const float* __restrict__ relpos,
    const float* __restrict__ Wout,
    const float* __restrict__ bout,
    const f16* __restrict__ ws,
    float* __restrict__ out)
{
  __shared__ __align__(16) f16 smem[10000 * 8];   // 160000 B arena
  int* s_addr = (int*)&smem[G_ADDR * 8];

  const int tid = threadIdx.x;
  const int wi = blockIdx.x >> 6, wj = blockIdx.x & 63;
  const int wv = tid >> 6;
  const int l = tid & 63;
  const int l15 = l & 15, lg = l >> 4;
  const f32x4 zero4 = {0.f, 0.f, 0.f, 0.f};
  const float QMULT = 0.17677669529663687f * 1.4426950408889634f; // scale*log2e

  // ---------------- Phase 0: scatter LUT + rolled x window (f16) ------------
  if (tid < 64) {
    int val = 0;
    if (tid < 49) {
      int i2 = tid / 7, j2 = tid - i2 * 7;
      int y = (wi & 15) * 7 + i2 + 3;  if (y >= 112) y -= 112;
      int xc = wj * 7 + j2 + 3;        if (xc >= 448) xc -= 448;
      val = (y * 448 + xc) * 768;
    }
    s_addr[tid] = val;
  }
  for (int gid = tid; gid < 1536; gid += 1024) {
    int t = gid / 24, g = gid - t * 24;
    f16x8 v;
    if (t < 49) {
      int hh = wi * 7 + t / 7 + 3; if (hh >= 448) hh -= 448;
      int ww = wj * 7 + t % 7 + 3; if (ww >= 448) ww -= 448;
      v = cvt8z(x + (size_t)(hh * 448 + ww) * 192 + g * 8);
    } else {
#pragma unroll
      for (int e = 0; e < 8; ++e) v[e] = (f16)0.0f;
    }
    *(f16x8*)&smem[(G_XIN + t * 25 + g) * 8] = v;
  }
  __syncthreads();

  // ---------------- Phase 1: QKV. waves 0-11: q/k (swapped); 12-15: v -------
  if (wv < 12) {
    f32x4 aqk[2][4];
#pragma unroll
    for (int ci = 0; ci < 2; ++ci)
#pragma unroll
      for (int t = 0; t < 4; ++t) aqk[ci][t] = zero4;

#pragma unroll
    for (int kc = 0; kc < 6; ++kc) {
      f16x8 xf[4];
#pragma unroll
      for (int t = 0; t < 4; ++t)
        xf[t] = *(const f16x8*)&smem[(G_XIN + (t * 16 + l15) * 25 + kc * 4 + lg) * 8];
      f16x8 wq0 = load_bq<USE_WS>(ws, Wqkv, kc, 2 * wv, l);
      f16x8 wq1 = load_bq<USE_WS>(ws, Wqkv, kc, 2 * wv + 1, l);
#pragma unroll
      for (int t = 0; t < 4; ++t) aqk[0][t] = MFMA16(wq0, xf[t], aqk[0][t]);
#pragma unroll
      for (int t = 0; t < 4; ++t) aqk[1][t] = MFMA16(wq1, xf[t], aqk[1][t]);
    }

#pragma unroll
    for (int ci = 0; ci < 2; ++ci) {
      int c0 = (2 * wv + ci) * 16 + lg * 4;       // 0..383
      float4 b4 = *(const float4*)(bqkv + c0);
      int part = (c0 >= 192) ? 1 : 0;
      int ch = c0 - part * 192;
      float mult = part ? 1.0f : QMULT;
      float bx = b4.x * mult, by = b4.y * mult, bz = b4.z * mult, bw = b4.w * mult;
      int gbase = (part ? G_K : G_Q) + (ch >> 3);
      int sub = ch & 7;
#pragma unroll
      for (int t = 0; t < 4; ++t) {
        int tok = t * 16 + l15;
        f16x4 v = pk4(fmaf(aqk[ci][t][0], mult, bx), fmaf(aqk[ci][t][1], mult, by),
                      fmaf(aqk[ci][t][2], mult, bz), fmaf(aqk[ci][t][3], mult, bw));
        *(f16x4*)&smem[(gbase + tok * 25) * 8 + sub] = v;
      }
    }
  } else {
    const int cv0 = (wv - 12) * 3;
    f32x4 av[3][4];
#pragma unroll
    for (int ci = 0; ci < 3; ++ci)
#pragma unroll
      for (int t = 0; t < 4; ++t) av[ci][t] = zero4;

#pragma unroll
    for (int kc = 0; kc < 6; ++kc) {
      f16x8 xf[4];
#pragma unroll
      for (int t = 0; t < 4; ++t)
        xf[t] = *(const f16x8*)&smem[(G_XIN + (t * 16 + l15) * 25 + kc * 4 + lg) * 8];
      f16x8 w0 = load_bq<USE_WS>(ws, Wqkv, kc, 24 + cv0, l);
      f16x8 w1 = load_bq<USE_WS>(ws, Wqkv, kc, 24 + cv0 + 1, l);
      f16x8 w2 = load_bq<USE_WS>(ws, Wqkv, kc, 24 + cv0 + 2, l);
#pragma unroll
      for (int t = 0; t < 4; ++t) {
        av[0][t] = MFMA16(xf[t], w0, av[0][t]);
        av[1][t] = MFMA16(xf[t], w1, av[1][t]);
        av[2][t] = MFMA16(xf[t], w2, av[2][t]);
      }
    }

#pragma unroll
    for (int ci = 0; ci < 3; ++ci) {
      int vch = (cv0 + ci) * 16 + l15;            // 0..191
      float bv_ = bqkv[384 + vch];
#pragma unroll
      for (int t = 0; t < 4; ++t) {
        f16x4 v = pk4(av[ci][t][0] + bv_, av[ci][t][1] + bv_,
                      av[ci][t][2] + bv_, av[ci][t][3] + bv_);
        *(f16x4*)&smem[(G_VT + vch * 9 + 2 * t + (lg >> 1)) * 8 + (lg & 1) * 4] = v;
      }
    }
  }
  __syncthreads();

  // ---------------- Phase 2: attention ---------------------------------------
  {
    const int pt = wv & 3, hi = wv >> 2;
    const int p = 16 * pt + l15;
    const bool edge = (wi == 63) || (wj == 63);
    unsigned mbits = 0;
    int moff[16];
    if (edge || !USE_WS) {
      int pi = p / 7, pj = p - pi * 7;
#pragma unroll
      for (int jq = 0; jq < 4; ++jq)
#pragma unroll
        for (int r = 0; r < 4; ++r) {
          int q = 16 * jq + lg * 4 + r;
          int qi = q / 7, qj = q - qi * 7;
          bool bad = (q >= 49) || (p >= 49) ||
                     ((wi == 63) && ((pi < 4) != (qi < 4))) ||
                     ((wj == 63) && ((pj < 4) != (qj < 4)));
          int idx = jq * 4 + r;
          moff[idx] = bad ? 0 : (pi - qi + 6) * 13 + (pj - qj + 6);
          if (bad) mbits |= (1u << idx);
        }
    }

    if constexpr (USE_WS) {
      const float* bb_base = (const float*)(ws + WS_BIAS_ELEM) + p * 68 + lg * 4;
      if (hi < 2) attn_fast<2>(smem, bb_base, hi * 2, p, lg, l15, mbits, edge);
      else        attn_fast<1>(smem, bb_base, hi + 2, p, lg, l15, mbits, edge);
    } else {
      // fallback: sequential heads, per-lane global relpos gather
      const int h_first = (hi < 2) ? (hi * 2) : (hi + 2);
      const int h_count = (hi < 2) ? 2 : 1;
      float gaus[16];
#pragma unroll
      for (int jq = 0; jq < 4; ++jq)
#pragma unroll
        for (int r = 0; r < 4; ++r) {
          int q = 16 * jq + lg * 4 + r;
          int qi = q / 7, qj = q - qi * 7;
          int pi = p / 7, pj = p - pi * 7;
          int di = pi - qi, dj = pj - qj;
          gaus[jq * 4 + r] = __expf((float)(di * di + dj * dj) * (-9.0f / 98.0f));
        }
      for (int e = 0; e < h_count; ++e) {
        int h = h_first + e;
        f16x8 aq = *(const f16x8*)&smem[(G_Q + p * 25 + h * 4 + lg) * 8];
        f32x4 sc[4];
#pragma unroll
        for (int jq = 0; jq < 4; ++jq) {
          f16x8 bk = *(const f16x8*)&smem[(G_K + (16 * jq + l15) * 25 + h * 4 + lg) * 8];
          sc[jq] = MFMA16(bk, aq, zero4);
        }
        float sv[16];
        float sum = 0.0f;
#pragma unroll
        for (int jq = 0; jq < 4; ++jq)
#pragma unroll
          for (int r = 0; r < 4; ++r) {
            int idx = jq * 4 + r;
            float s = (mbits >> idx & 1u)
                ? -30000.0f
                : sc[jq][r] + (relpos[h * 169 + moff[idx]] + gaus[idx]) * 1.4426950408889634f;
            float ev = exp2f(s);
            sv[idx] = ev;
            sum += ev;
          }
#pragma unroll
        for (int jq = 0; jq < 4; ++jq) {
          f16x4 v = pk4(sv[jq * 4], sv[jq * 4 + 1], sv[jq * 4 + 2], sv[jq * 4 + 3]);
          *(f16x4*)&smem[(G_P + h * 576 + p * 9 + 2 * jq + (lg >> 1)) * 8 + (lg & 1) * 4] = v;
        }
        sum += __shfl_xor(sum, 16);
        sum += __shfl_xor(sum, 32);
        float inv = __builtin_amdgcn_rcpf(sum);
        f32x4 o[2] = {zero4, zero4};
#pragma unroll
        for (int kq = 0; kq < 2; ++kq) {
          f16x8 ap = *(const f16x8*)&smem[(G_P + h * 576 + p * 9 + kq * 4 + lg) * 8];
#pragma unroll
          for (int jn = 0; jn < 2; ++jn) {
            int ch = h * 32 + jn * 16 + l15;
            f16x8 bv = *(const f16x8*)&smem[(G_VT + ch * 9 + kq * 4 + lg) * 8];
            o[jn] = MFMA16(bv, ap, o[jn]);
          }
        }
#pragma unroll
        for (int jn = 0; jn < 2; ++jn) {
          int ch0 = h * 32 + jn * 16 + lg * 4;
          f16x4 v = pk4(o[jn][0] * inv, o[jn][1] * inv, o[jn][2] * inv, o[jn][3] * inv);
          *(f16x4*)&smem[(G_O + p * 25 + (ch0 >> 3)) * 8 + (ch0 & 7)] = v;
        }
      }
    }
  }
  __syncthreads();

  // ---------------- Phase 3: out-proj + LUT scatter -------------------------
  {
    const int tt = wv >> 2, cg = wv & 3;
    f32x4 acc3[3];
#pragma unroll
    for (int j = 0; j < 3; ++j) acc3[j] = zero4;

#pragma unroll
    for (int kc = 0; kc < 6; ++kc) {
      f16x8 a = *(const f16x8*)&smem[(G_O + (tt * 16 + l15) * 25 + kc * 4 + lg) * 8];
      f16x8 b0 = load_bo<USE_WS>(ws, Wout, kc, 3 * cg, l);
      f16x8 b1 = load_bo<USE_WS>(ws, Wout, kc, 3 * cg + 1, l);
      f16x8 b2 = load_bo<USE_WS>(ws, Wout, kc, 3 * cg + 2, l);
      acc3[0] = MFMA16(a, b0, acc3[0]);
      acc3[1] = MFMA16(a, b1, acc3[1]);
      acc3[2] = MFMA16(a, b2, acc3[2]);
    }

    const int rr = wi >> 4;
    const int lane_off = rr * 192 + cg * 48 + l15;
    const float bias0 = bout[cg * 48 + l15];
    const float bias1 = bout[cg * 48 + 16 + l15];
    const float bias2 = bout[cg * 48 + 32 + l15];
#pragma unroll
    for (int r = 0; r < 4; ++r) {
      int pp = tt * 16 + lg * 4 + r;
      if (pp < 49) {
        float* base = out + s_addr[pp] + lane_off;
        __builtin_nontemporal_store(acc3[0][r] + bias0, base);
        __builtin_nontemporal_store(acc3[1][r] + bias1, base + 16);
        __builtin_nontemporal_store(acc3[2][r] + bias2, base + 32);
      }
    }
  }
}

extern "C" void kernel_launch(void* const* d_in, const int* in_sizes, int n_in,
                              void* d_out, int out_size, void* d_ws, size_t ws_size,
                              hipStream_t stream) {
  const float* x      = (const float*)d_in[0];
  const float* Wqkv   = (const float*)d_in[1];
  const float* bqkv   = (const float*)d_in[2];
  const float* relpos = (const float*)d_in[3];
  const float* Wout   = (const float*)d_in[4];
  const float* bout   = (const float*)d_in[5];
  float* out = (float*)d_out;
  f16* ws = (f16*)d_ws;

  if (ws_size >= (size_t)WS_NEED) {
    wmsa_prep<<<174, 256, 0, stream>>>(Wqkv, Wout, relpos, ws);
    wmsa_main<true><<<4096, 1024, 0, stream>>>(x, Wqkv, bqkv, relpos, Wout, bout, ws, out);
  } else {
    wmsa_main<false><<<4096, 1024, 0, stream>>>(x, Wqkv, bqkv, relpos, Wout, bout, ws, out);
  }
}